// Round 1
// baseline (1617.946 us; speedup 1.0000x reference)
//
#include <hip/hip_runtime.h>
#include <cstdint>
#include <cstddef>

#define NN 50000
#define NE 800000
#define HD 128

// ---------------- degree histogram ----------------
__global__ __launch_bounds__(256) void deg_kernel(const int* __restrict__ src, const int* __restrict__ dst,
                                                  int* __restrict__ outcnt, int* __restrict__ incnt, int e) {
  int i = blockIdx.x * 256 + threadIdx.x;
  if (i < e) {
    atomicAdd(&outcnt[src[i]], 1);
    atomicAdd(&incnt[dst[i]], 1);
  }
}

__global__ __launch_bounds__(256) void rs_kernel(const int* __restrict__ outcnt, const int* __restrict__ incnt,
                                                 float* __restrict__ rs_out, float* __restrict__ rs_in, int n) {
  int i = blockIdx.x * 256 + threadIdx.x;
  if (i < n) {
    int oc = outcnt[i] > 1 ? outcnt[i] : 1;
    int ic = incnt[i] > 1 ? incnt[i] : 1;
    rs_out[i] = rsqrtf((float)oc);
    rs_in[i] = rsqrtf((float)ic);
  }
}

// ---------------- exclusive scan (3-kernel) ----------------
__global__ __launch_bounds__(256) void scan1_kernel(const int* __restrict__ cnt, int* __restrict__ excl,
                                                    int* __restrict__ bsum, int n) {
  __shared__ int sh[256];
  int i = blockIdx.x * 256 + threadIdx.x;
  int v = (i < n) ? cnt[i] : 0;
  sh[threadIdx.x] = v;
  __syncthreads();
  for (int off = 1; off < 256; off <<= 1) {
    int x = (threadIdx.x >= off) ? sh[threadIdx.x - off] : 0;
    __syncthreads();
    sh[threadIdx.x] += x;
    __syncthreads();
  }
  if (i < n) excl[i] = sh[threadIdx.x] - v;
  if (threadIdx.x == 255) bsum[blockIdx.x] = sh[255];
}

__global__ __launch_bounds__(256) void scan2_kernel(int* __restrict__ bsum, int nb) {
  __shared__ int sh[256];
  int v = (threadIdx.x < nb) ? bsum[threadIdx.x] : 0;
  sh[threadIdx.x] = v;
  __syncthreads();
  for (int off = 1; off < 256; off <<= 1) {
    int x = (threadIdx.x >= off) ? sh[threadIdx.x - off] : 0;
    __syncthreads();
    sh[threadIdx.x] += x;
    __syncthreads();
  }
  if (threadIdx.x < nb) bsum[threadIdx.x] = sh[threadIdx.x] - v;
}

__global__ __launch_bounds__(256) void scan3_kernel(const int* __restrict__ excl, const int* __restrict__ bsum,
                                                    int* __restrict__ row_ptr, int* __restrict__ cursor,
                                                    int n, int e) {
  int i = blockIdx.x * 256 + threadIdx.x;
  if (i < n) {
    int v = excl[i] + bsum[blockIdx.x];
    row_ptr[i] = v;
    cursor[i] = v;
  }
  if (i == 0) row_ptr[n] = e;
}

__global__ __launch_bounds__(256) void fill_kernel(const int* __restrict__ src, const int* __restrict__ dst,
                                                   int* __restrict__ cursor, int* __restrict__ csr_src, int e) {
  int i = blockIdx.x * 256 + threadIdx.x;
  if (i < e) {
    int pos = atomicAdd(&cursor[dst[i]], 1);
    csr_src[pos] = src[i];
  }
}

// ---------------- dense [n,128]@[128,128] with fused rank-1 term + per-row scale ----------------
// C[r][c] = (sum_k A[r][k]*W[k][c] + evec[r]*erow[c]) * rs[r]
__global__ __launch_bounds__(256) void mm128_kernel(const float* __restrict__ A, const float* __restrict__ W,
                                                    const float* __restrict__ rs, const float* __restrict__ evec,
                                                    const float* __restrict__ erow, float* __restrict__ C, int n) {
  __shared__ float Wl[HD * HD];  // 64 KB, bank-conflict-free reads (bank = c%32, 2-way)
  for (int i = threadIdx.x; i < HD * HD; i += 256) Wl[i] = W[i];
  __syncthreads();
  const int c = threadIdx.x & 127;
  const int rg = threadIdx.x >> 7;
  const int r0 = blockIdx.x * 32 + rg * 16;
  if (r0 >= n) return;
  int rb[16];
#pragma unroll
  for (int i = 0; i < 16; i++) {
    int r = r0 + i;
    if (r > n - 1) r = n - 1;  // clamp: valid read, result discarded on write
    rb[i] = r * HD;
  }
  float acc[16];
#pragma unroll
  for (int i = 0; i < 16; i++) acc[i] = 0.f;
  for (int k = 0; k < HD; k += 4) {
    float w0 = Wl[k * HD + c], w1 = Wl[(k + 1) * HD + c];
    float w2 = Wl[(k + 2) * HD + c], w3 = Wl[(k + 3) * HD + c];
#pragma unroll
    for (int i = 0; i < 16; i++) {
      float4 a = *reinterpret_cast<const float4*>(A + rb[i] + k);  // wave-broadcast, L1-hit
      acc[i] = fmaf(a.x, w0, acc[i]);
      acc[i] = fmaf(a.y, w1, acc[i]);
      acc[i] = fmaf(a.z, w2, acc[i]);
      acc[i] = fmaf(a.w, w3, acc[i]);
    }
  }
  float er = (evec != nullptr) ? erow[c] : 0.f;
#pragma unroll
  for (int i = 0; i < 16; i++) {
    int r = r0 + i;
    if (r < n) {
      float v = acc[i];
      if (evec != nullptr) v = fmaf(evec[r], er, v);
      if (rs != nullptr) v *= rs[r];
      C[(size_t)r * HD + c] = v;
    }
  }
}

// ---------------- pull-mode normalized aggregation (one wave per dst node) ----------------
// out[d] = rs_in[d] * sum_{e in CSR[d]} Ys[src_e]  + bias   (optional lrelu)
__global__ __launch_bounds__(256) void agg_kernel(const float* __restrict__ Ys, const int* __restrict__ row_ptr,
                                                  const int* __restrict__ csr_src, const float* __restrict__ rs_in,
                                                  const float* __restrict__ bias, float* __restrict__ out,
                                                  int n, int do_lrelu) {
  int wave = threadIdx.x >> 6;
  int lane = threadIdx.x & 63;
  int node = blockIdx.x * 4 + wave;
  if (node >= n) return;
  int beg = row_ptr[node], end = row_ptr[node + 1];
  float ax = 0.f, ay = 0.f;
  for (int e = beg; e < end; ++e) {
    int s = csr_src[e];
    float2 v = reinterpret_cast<const float2*>(Ys + (size_t)s * HD)[lane];
    ax += v.x;
    ay += v.y;
  }
  float ri = rs_in[node];
  float2 b = reinterpret_cast<const float2*>(bias)[lane];
  float ox = fmaf(ax, ri, b.x);
  float oy = fmaf(ay, ri, b.y);
  if (do_lrelu) {
    ox = ox >= 0.f ? ox : 0.01f * ox;
    oy = oy >= 0.f ? oy : 0.01f * oy;
  }
  reinterpret_cast<float2*>(out + (size_t)node * HD)[lane] = make_float2(ox, oy);
}

// ---------------- BN statistics (column sums / sumsq) ----------------
__global__ __launch_bounds__(256) void stats_kernel(const float* __restrict__ Z, int n, float* __restrict__ sums) {
  int c = threadIdx.x & 127;
  int half = threadIdx.x >> 7;
  float s = 0.f, s2 = 0.f;
  for (int r = blockIdx.x * 2 + half; r < n; r += gridDim.x * 2) {
    float v = Z[(size_t)r * HD + c];
    s += v;
    s2 = fmaf(v, v, s2);
  }
  __shared__ float ls[512];
  ls[threadIdx.x] = s;
  ls[256 + threadIdx.x] = s2;
  __syncthreads();
  if (threadIdx.x < 128) {
    atomicAdd(&sums[c], ls[threadIdx.x] + ls[threadIdx.x + 128]);
    atomicAdd(&sums[128 + c], ls[256 + threadIdx.x] + ls[256 + threadIdx.x + 128]);
  }
}

__global__ void bnfin_kernel(const float* __restrict__ sums, const float* __restrict__ gamma,
                             const float* __restrict__ beta, float* __restrict__ bnp, float n) {
  int c = threadIdx.x;  // 128
  float mu = sums[c] / n;
  float var = sums[128 + c] / n - mu * mu;
  if (var < 0.f) var = 0.f;
  float sc = gamma[c] * rsqrtf(var + 1e-5f);
  bnp[c] = sc;
  bnp[128 + c] = fmaf(-mu, sc, beta[c]);
}

__global__ __launch_bounds__(256) void bnapply_kernel(const float* __restrict__ Z, const float* __restrict__ bnp,
                                                      float* __restrict__ H, int n) {
  size_t idx = ((size_t)blockIdx.x * 256 + threadIdx.x) * 2;
  if (idx >= (size_t)n * HD) return;
  float2 v = *reinterpret_cast<const float2*>(Z + idx);
  int c = (int)(idx & 127);
  float a = fmaf(v.x, bnp[c], bnp[128 + c]);
  float b = fmaf(v.y, bnp[c + 1], bnp[129 + c]);
  a = a >= 0.f ? a : 0.01f * a;
  b = b >= 0.f ? b : 0.01f * b;
  *reinterpret_cast<float2*>(H + idx) = make_float2(a, b);
}

// ---------------- node_out = X@Wnc + b_nc  ([n,128]@[128,8]) ----------------
__global__ __launch_bounds__(256) void nodeout_kernel(const float* __restrict__ X, const float* __restrict__ Wnc,
                                                      const float* __restrict__ b, float* __restrict__ out, int n) {
  __shared__ float Wl[HD * 8];
  __shared__ float bl[8];
  for (int i = threadIdx.x; i < HD * 8; i += 256) Wl[i] = Wnc[i];
  if (threadIdx.x < 8) bl[threadIdx.x] = b[threadIdx.x];
  __syncthreads();
  int t = blockIdx.x * 256 + threadIdx.x;
  int r = t >> 3, c = t & 7;
  if (r >= n) return;
  const float* x = X + (size_t)r * HD;
  float acc = bl[c];
  for (int k = 0; k < HD; k += 4) {
    float4 a = *reinterpret_cast<const float4*>(x + k);
    acc = fmaf(a.x, Wl[k * 8 + c], acc);
    acc = fmaf(a.y, Wl[(k + 1) * 8 + c], acc);
    acc = fmaf(a.z, Wl[(k + 2) * 8 + c], acc);
    acc = fmaf(a.w, Wl[(k + 3) * 8 + c], acc);
  }
  out[(size_t)r * 8 + c] = acc;
}

// ---------------- graph segment-sum ----------------
__global__ __launch_bounds__(256) void gsum_kernel(const float* __restrict__ HG, const int* __restrict__ gid,
                                                   float* __restrict__ hsum, int* __restrict__ gcnt, int n) {
  int i = blockIdx.x * 256 + threadIdx.x;
  if (i >= n * HD) return;
  int r = i >> 7, c = i & 127;
  int g = gid[r];
  atomicAdd(&hsum[g * HD + c], HG[i]);
  if (c == 0) atomicAdd(&gcnt[g], 1);
}

__global__ void gout_kernel(const float* __restrict__ hsum, const int* __restrict__ gcnt,
                            const float* __restrict__ Wgc, const float* __restrict__ bgc, float* __restrict__ out) {
  int t = threadIdx.x;  // 256 = 64 graphs * 4 cols
  int g = t >> 2, c = t & 3;
  float cnt = (float)gcnt[g];
  float inv = 1.f / (cnt > 1.f ? cnt : 1.f);
  float acc = bgc[c];
  for (int k = 0; k < HD; k++) acc = fmaf(hsum[g * HD + k] * inv, Wgc[k * 4 + c], acc);
  out[t] = acc;
}

extern "C" void kernel_launch(void* const* d_in, const int* in_sizes, int n_in,
                              void* d_out, int out_size, void* d_ws, size_t ws_size,
                              hipStream_t stream) {
  const float* node_feat = (const float*)d_in[0];
  const float* nodetype = (const float*)d_in[1];
  // d_in[2] edge_feat: dead branch, unused
  const float* W1 = (const float*)d_in[3];
  const float* b1 = (const float*)d_in[4];
  const float* g1 = (const float*)d_in[5];
  const float* be1 = (const float*)d_in[6];
  const float* W2 = (const float*)d_in[7];
  const float* b2 = (const float*)d_in[8];
  const float* g2 = (const float*)d_in[9];
  const float* be2 = (const float*)d_in[10];
  // 11 We, 12 b_e: dead
  const float* Wn1 = (const float*)d_in[13];
  const float* bn1 = (const float*)d_in[14];
  const float* Wn2 = (const float*)d_in[15];
  const float* bn2 = (const float*)d_in[16];
  const float* Wnc = (const float*)d_in[17];
  const float* bnc = (const float*)d_in[18];
  const float* Wg1 = (const float*)d_in[19];
  const float* bg1 = (const float*)d_in[20];
  const float* Wgc = (const float*)d_in[21];
  const float* bgc = (const float*)d_in[22];
  const int* src = (const int*)d_in[23];
  const int* dst = (const int*)d_in[24];
  const int* gid = (const int*)d_in[25];

  const int n = NN, e = NE;

  // ---- workspace carve (256B aligned) ----
  char* w = (char*)d_ws;
  auto alloc = [&](size_t bytes) -> void* {
    void* p = (void*)w;
    w += (bytes + 255) & ~(size_t)255;
    return p;
  };
  float* Hb = (float*)alloc((size_t)n * HD * 4);
  float* S1 = (float*)alloc((size_t)n * HD * 4);
  float* S2 = (float*)alloc((size_t)n * HD * 4);
  int* csr_src = (int*)alloc((size_t)e * 4);
  int* row_ptr = (int*)alloc((size_t)(n + 1) * 4);
  int* cursor = (int*)alloc((size_t)n * 4);
  int* outcnt = (int*)alloc((size_t)n * 4);
  int* incnt = (int*)alloc((size_t)n * 4);
  int* excl = (int*)alloc((size_t)n * 4);
  int* bsum = (int*)alloc(256 * 4);
  float* rs_out = (float*)alloc((size_t)n * 4);
  float* rs_in = (float*)alloc((size_t)n * 4);
  float* sums = (float*)alloc(256 * 4);
  float* bnp = (float*)alloc(256 * 4);
  float* hsum = (float*)alloc(64 * HD * 4);
  int* gcnt = (int*)alloc(64 * 4);

  const int EB = (e + 255) / 256;        // 3125
  const int NB = (n + 255) / 256;        // 196
  const int MMB = (n + 31) / 32;         // 1563
  const int AGB = (n + 3) / 4;           // 12500
  const int ELB = ((n * HD / 2) + 255) / 256;  // 12500
  const int NOB = (n * 8 + 255) / 256;   // 1563
  const int GSB = ((size_t)n * HD + 255) / 256;  // 25000

  // ---- degrees + CSR build (per call; deterministic inputs) ----
  hipMemsetAsync(outcnt, 0, (size_t)n * 4, stream);
  hipMemsetAsync(incnt, 0, (size_t)n * 4, stream);
  deg_kernel<<<EB, 256, 0, stream>>>(src, dst, outcnt, incnt, e);
  rs_kernel<<<NB, 256, 0, stream>>>(outcnt, incnt, rs_out, rs_in, n);
  scan1_kernel<<<NB, 256, 0, stream>>>(incnt, excl, bsum, n);
  scan2_kernel<<<1, 256, 0, stream>>>(bsum, NB);
  scan3_kernel<<<NB, 256, 0, stream>>>(excl, bsum, row_ptr, cursor, n, e);
  fill_kernel<<<EB, 256, 0, stream>>>(src, dst, cursor, csr_src, e);

  // ---- layer 1: h = lrelu(bn(gconv(node_feat, W1, b1))) ----
  mm128_kernel<<<MMB, 256, 0, stream>>>(node_feat, W1, rs_out, nullptr, nullptr, S1, n);
  agg_kernel<<<AGB, 256, 0, stream>>>(S1, row_ptr, csr_src, rs_in, b1, S2, n, 0);
  hipMemsetAsync(sums, 0, 256 * 4, stream);
  stats_kernel<<<256, 256, 0, stream>>>(S2, n, sums);
  bnfin_kernel<<<1, 128, 0, stream>>>(sums, g1, be1, bnp, (float)n);
  bnapply_kernel<<<ELB, 256, 0, stream>>>(S2, bnp, Hb, n);

  // ---- layer 2: h = lrelu(bn(gconv(h, W2, b2))) ----
  mm128_kernel<<<MMB, 256, 0, stream>>>(Hb, W2, rs_out, nullptr, nullptr, S1, n);
  agg_kernel<<<AGB, 256, 0, stream>>>(S1, row_ptr, csr_src, rs_in, b2, S2, n, 0);
  hipMemsetAsync(sums, 0, 256 * 4, stream);
  stats_kernel<<<256, 256, 0, stream>>>(S2, n, sums);
  bnfin_kernel<<<1, 128, 0, stream>>>(sums, g2, be2, bnp, (float)n);
  bnapply_kernel<<<ELB, 256, 0, stream>>>(S2, bnp, Hb, n);

  // ---- layer 3: hn = lrelu(gconv(h, Wn1, b_nn1)) ----
  mm128_kernel<<<MMB, 256, 0, stream>>>(Hb, Wn1, rs_out, nullptr, nullptr, S1, n);
  agg_kernel<<<AGB, 256, 0, stream>>>(S1, row_ptr, csr_src, rs_in, bn1, S2, n, 1);

  // ---- layer 4: hn = lrelu(gconv(hn, Wn2, b_nn2)) ----
  mm128_kernel<<<MMB, 256, 0, stream>>>(S2, Wn2, rs_out, nullptr, nullptr, S1, n);
  agg_kernel<<<AGB, 256, 0, stream>>>(S1, row_ptr, csr_src, rs_in, bn2, S2, n, 1);

  // ---- node_out = hn @ Wnc + b_nc ----
  nodeout_kernel<<<NOB, 256, 0, stream>>>(S2, Wnc, bnc, (float*)d_out, n);

  // ---- layer 5: hg = lrelu(gconv([h|nodetype], Wg1, b_g1)) via rank-1 fold ----
  mm128_kernel<<<MMB, 256, 0, stream>>>(Hb, Wg1, rs_out, nodetype, Wg1 + HD * HD, S1, n);
  agg_kernel<<<AGB, 256, 0, stream>>>(S1, row_ptr, csr_src, rs_in, bg1, S2, n, 1);

  // ---- graph mean + graph_out ----
  hipMemsetAsync(hsum, 0, 64 * HD * 4, stream);
  hipMemsetAsync(gcnt, 0, 64 * 4, stream);
  gsum_kernel<<<GSB, 256, 0, stream>>>(S2, gid, hsum, gcnt, n);
  gout_kernel<<<1, 256, 0, stream>>>(hsum, gcnt, Wgc, bgc, (float*)d_out + (size_t)n * 8);
}

// Round 2
// 1351.663 us; speedup vs baseline: 1.1970x; 1.1970x over previous
//
#include <hip/hip_runtime.h>
#include <cstdint>
#include <cstddef>

#define NN 50000
#define NE 800000
#define HD 128

// ---------------- degree histogram ----------------
__global__ __launch_bounds__(256) void deg_kernel(const int* __restrict__ src, const int* __restrict__ dst,
                                                  int* __restrict__ outcnt, int* __restrict__ incnt, int e) {
  int i = blockIdx.x * 256 + threadIdx.x;
  if (i < e) {
    atomicAdd(&outcnt[src[i]], 1);
    atomicAdd(&incnt[dst[i]], 1);
  }
}

__global__ __launch_bounds__(256) void rs_kernel(const int* __restrict__ outcnt, const int* __restrict__ incnt,
                                                 float* __restrict__ rs_out, float* __restrict__ rs_in, int n) {
  int i = blockIdx.x * 256 + threadIdx.x;
  if (i < n) {
    int oc = outcnt[i] > 1 ? outcnt[i] : 1;
    int ic = incnt[i] > 1 ? incnt[i] : 1;
    rs_out[i] = rsqrtf((float)oc);
    rs_in[i] = rsqrtf((float)ic);
  }
}

// ---------------- exclusive scan (3-kernel) ----------------
__global__ __launch_bounds__(256) void scan1_kernel(const int* __restrict__ cnt, int* __restrict__ excl,
                                                    int* __restrict__ bsum, int n) {
  __shared__ int sh[256];
  int i = blockIdx.x * 256 + threadIdx.x;
  int v = (i < n) ? cnt[i] : 0;
  sh[threadIdx.x] = v;
  __syncthreads();
  for (int off = 1; off < 256; off <<= 1) {
    int x = (threadIdx.x >= off) ? sh[threadIdx.x - off] : 0;
    __syncthreads();
    sh[threadIdx.x] += x;
    __syncthreads();
  }
  if (i < n) excl[i] = sh[threadIdx.x] - v;
  if (threadIdx.x == 255) bsum[blockIdx.x] = sh[255];
}

__global__ __launch_bounds__(256) void scan2_kernel(int* __restrict__ bsum, int nb) {
  __shared__ int sh[256];
  int v = (threadIdx.x < nb) ? bsum[threadIdx.x] : 0;
  sh[threadIdx.x] = v;
  __syncthreads();
  for (int off = 1; off < 256; off <<= 1) {
    int x = (threadIdx.x >= off) ? sh[threadIdx.x - off] : 0;
    __syncthreads();
    sh[threadIdx.x] += x;
    __syncthreads();
  }
  if (threadIdx.x < nb) bsum[threadIdx.x] = sh[threadIdx.x] - v;
}

__global__ __launch_bounds__(256) void scan3_kernel(const int* __restrict__ excl, const int* __restrict__ bsum,
                                                    int* __restrict__ row_ptr, int* __restrict__ cursor,
                                                    int n, int e) {
  int i = blockIdx.x * 256 + threadIdx.x;
  if (i < n) {
    int v = excl[i] + bsum[blockIdx.x];
    row_ptr[i] = v;
    cursor[i] = v;
  }
  if (i == 0) row_ptr[n] = e;
}

__global__ __launch_bounds__(256) void fill_kernel(const int* __restrict__ src, const int* __restrict__ dst,
                                                   int* __restrict__ cursor, int* __restrict__ csr_src, int e) {
  int i = blockIdx.x * 256 + threadIdx.x;
  if (i < e) {
    int pos = atomicAdd(&cursor[dst[i]], 1);
    csr_src[pos] = src[i];
  }
}

// ---------------- dense [n,128]@[128,128] with fused rank-1 term + per-row scale ----------------
// C[r][c] = (sum_k A[r][k]*W[k][c] + evec[r]*erow[c]) * rs[r]
__global__ __launch_bounds__(256) void mm128_kernel(const float* __restrict__ A, const float* __restrict__ W,
                                                    const float* __restrict__ rs, const float* __restrict__ evec,
                                                    const float* __restrict__ erow, float* __restrict__ C, int n) {
  __shared__ float Wl[HD * HD];  // 64 KB, bank-conflict-free reads (bank = c%32, 2-way)
  for (int i = threadIdx.x; i < HD * HD; i += 256) Wl[i] = W[i];
  __syncthreads();
  const int c = threadIdx.x & 127;
  const int rg = threadIdx.x >> 7;
  const int r0 = blockIdx.x * 32 + rg * 16;
  if (r0 >= n) return;
  int rb[16];
#pragma unroll
  for (int i = 0; i < 16; i++) {
    int r = r0 + i;
    if (r > n - 1) r = n - 1;  // clamp: valid read, result discarded on write
    rb[i] = r * HD;
  }
  float acc[16];
#pragma unroll
  for (int i = 0; i < 16; i++) acc[i] = 0.f;
  for (int k = 0; k < HD; k += 4) {
    float w0 = Wl[k * HD + c], w1 = Wl[(k + 1) * HD + c];
    float w2 = Wl[(k + 2) * HD + c], w3 = Wl[(k + 3) * HD + c];
#pragma unroll
    for (int i = 0; i < 16; i++) {
      float4 a = *reinterpret_cast<const float4*>(A + rb[i] + k);  // wave-broadcast, L1-hit
      acc[i] = fmaf(a.x, w0, acc[i]);
      acc[i] = fmaf(a.y, w1, acc[i]);
      acc[i] = fmaf(a.z, w2, acc[i]);
      acc[i] = fmaf(a.w, w3, acc[i]);
    }
  }
  float er = (evec != nullptr) ? erow[c] : 0.f;
#pragma unroll
  for (int i = 0; i < 16; i++) {
    int r = r0 + i;
    if (r < n) {
      float v = acc[i];
      if (evec != nullptr) v = fmaf(evec[r], er, v);
      if (rs != nullptr) v *= rs[r];
      C[(size_t)r * HD + c] = v;
    }
  }
}

// ---------------- pull-mode normalized aggregation (one wave per dst node) ----------------
// out[d] = rs_in[d] * sum_{e in CSR[d]} Ys[src_e]  + bias   (optional lrelu)
__global__ __launch_bounds__(256) void agg_kernel(const float* __restrict__ Ys, const int* __restrict__ row_ptr,
                                                  const int* __restrict__ csr_src, const float* __restrict__ rs_in,
                                                  const float* __restrict__ bias, float* __restrict__ out,
                                                  int n, int do_lrelu) {
  int wave = threadIdx.x >> 6;
  int lane = threadIdx.x & 63;
  int node = blockIdx.x * 4 + wave;
  if (node >= n) return;
  int beg = row_ptr[node], end = row_ptr[node + 1];
  float ax = 0.f, ay = 0.f;
  for (int e = beg; e < end; ++e) {
    int s = csr_src[e];
    float2 v = reinterpret_cast<const float2*>(Ys + (size_t)s * HD)[lane];
    ax += v.x;
    ay += v.y;
  }
  float ri = rs_in[node];
  float2 b = reinterpret_cast<const float2*>(bias)[lane];
  float ox = fmaf(ax, ri, b.x);
  float oy = fmaf(ay, ri, b.y);
  if (do_lrelu) {
    ox = ox >= 0.f ? ox : 0.01f * ox;
    oy = oy >= 0.f ? oy : 0.01f * oy;
  }
  reinterpret_cast<float2*>(out + (size_t)node * HD)[lane] = make_float2(ox, oy);
}

// ---------------- BN statistics (column sums / sumsq) ----------------
__global__ __launch_bounds__(256) void stats_kernel(const float* __restrict__ Z, int n, float* __restrict__ sums) {
  int c = threadIdx.x & 127;
  int half = threadIdx.x >> 7;
  float s = 0.f, s2 = 0.f;
  for (int r = blockIdx.x * 2 + half; r < n; r += gridDim.x * 2) {
    float v = Z[(size_t)r * HD + c];
    s += v;
    s2 = fmaf(v, v, s2);
  }
  __shared__ float ls[512];
  ls[threadIdx.x] = s;
  ls[256 + threadIdx.x] = s2;
  __syncthreads();
  if (threadIdx.x < 128) {
    atomicAdd(&sums[c], ls[threadIdx.x] + ls[threadIdx.x + 128]);
    atomicAdd(&sums[128 + c], ls[256 + threadIdx.x] + ls[256 + threadIdx.x + 128]);
  }
}

__global__ void bnfin_kernel(const float* __restrict__ sums, const float* __restrict__ gamma,
                             const float* __restrict__ beta, float* __restrict__ bnp, float n) {
  int c = threadIdx.x;  // 128
  float mu = sums[c] / n;
  float var = sums[128 + c] / n - mu * mu;
  if (var < 0.f) var = 0.f;
  float sc = gamma[c] * rsqrtf(var + 1e-5f);
  bnp[c] = sc;
  bnp[128 + c] = fmaf(-mu, sc, beta[c]);
}

__global__ __launch_bounds__(256) void bnapply_kernel(const float* __restrict__ Z, const float* __restrict__ bnp,
                                                      float* __restrict__ H, int n) {
  size_t idx = ((size_t)blockIdx.x * 256 + threadIdx.x) * 2;
  if (idx >= (size_t)n * HD) return;
  float2 v = *reinterpret_cast<const float2*>(Z + idx);
  int c = (int)(idx & 127);
  float a = fmaf(v.x, bnp[c], bnp[128 + c]);
  float b = fmaf(v.y, bnp[c + 1], bnp[129 + c]);
  a = a >= 0.f ? a : 0.01f * a;
  b = b >= 0.f ? b : 0.01f * b;
  *reinterpret_cast<float2*>(H + idx) = make_float2(a, b);
}

// ---------------- node_out = X@Wnc + b_nc  ([n,128]@[128,8]) ----------------
__global__ __launch_bounds__(256) void nodeout_kernel(const float* __restrict__ X, const float* __restrict__ Wnc,
                                                      const float* __restrict__ b, float* __restrict__ out, int n) {
  __shared__ float Wl[HD * 8];
  __shared__ float bl[8];
  for (int i = threadIdx.x; i < HD * 8; i += 256) Wl[i] = Wnc[i];
  if (threadIdx.x < 8) bl[threadIdx.x] = b[threadIdx.x];
  __syncthreads();
  int t = blockIdx.x * 256 + threadIdx.x;
  int r = t >> 3, c = t & 7;
  if (r >= n) return;
  const float* x = X + (size_t)r * HD;
  float acc = bl[c];
  for (int k = 0; k < HD; k += 4) {
    float4 a = *reinterpret_cast<const float4*>(x + k);
    acc = fmaf(a.x, Wl[k * 8 + c], acc);
    acc = fmaf(a.y, Wl[(k + 1) * 8 + c], acc);
    acc = fmaf(a.z, Wl[(k + 2) * 8 + c], acc);
    acc = fmaf(a.w, Wl[(k + 3) * 8 + c], acc);
  }
  out[(size_t)r * 8 + c] = acc;
}

// ---------------- per-graph mean + graph_out (gid is SORTED: contiguous ranges) ----------------
// block g: rows [lb(g), lb(g+1)); mean over rows; out[g][0:4] = mean @ Wgc + bgc
__global__ __launch_bounds__(256) void gmean_kernel(const float* __restrict__ HG, const int* __restrict__ gid,
                                                    const float* __restrict__ Wgc, const float* __restrict__ bgc,
                                                    float* __restrict__ out, int n) {
  const int g = blockIdx.x;  // 64 blocks
  // lower_bound on sorted gid (redundant per-thread, ~16 iters, negligible)
  int lo = 0, hi = n;
  while (lo < hi) { int mid = (lo + hi) >> 1; if (gid[mid] < g) lo = mid + 1; else hi = mid; }
  const int beg = lo;
  lo = 0; hi = n;
  while (lo < hi) { int mid = (lo + hi) >> 1; if (gid[mid] < g + 1) lo = mid + 1; else hi = mid; }
  const int end = lo;

  const int c = threadIdx.x & 127;
  const int half = threadIdx.x >> 7;
  float s = 0.f;
  for (int r = beg + half; r < end; r += 2)
    s += HG[(size_t)r * HD + c];  // coalesced: 128 consecutive lanes -> 128 consecutive floats

  __shared__ float sh[256];
  sh[threadIdx.x] = s;
  __syncthreads();
  float cntf = (float)(end - beg);
  float inv = 1.f / (cntf > 1.f ? cntf : 1.f);
  if (threadIdx.x < 128) sh[threadIdx.x] = (sh[threadIdx.x] + sh[threadIdx.x + 128]) * inv;
  __syncthreads();
  if (threadIdx.x < 4) {
    float acc = bgc[threadIdx.x];
    for (int k = 0; k < HD; k++) acc = fmaf(sh[k], Wgc[k * 4 + threadIdx.x], acc);
    out[g * 4 + threadIdx.x] = acc;
  }
}

extern "C" void kernel_launch(void* const* d_in, const int* in_sizes, int n_in,
                              void* d_out, int out_size, void* d_ws, size_t ws_size,
                              hipStream_t stream) {
  const float* node_feat = (const float*)d_in[0];
  const float* nodetype = (const float*)d_in[1];
  // d_in[2] edge_feat: dead branch, unused
  const float* W1 = (const float*)d_in[3];
  const float* b1 = (const float*)d_in[4];
  const float* g1 = (const float*)d_in[5];
  const float* be1 = (const float*)d_in[6];
  const float* W2 = (const float*)d_in[7];
  const float* b2 = (const float*)d_in[8];
  const float* g2 = (const float*)d_in[9];
  const float* be2 = (const float*)d_in[10];
  // 11 We, 12 b_e: dead
  const float* Wn1 = (const float*)d_in[13];
  const float* bn1 = (const float*)d_in[14];
  const float* Wn2 = (const float*)d_in[15];
  const float* bn2 = (const float*)d_in[16];
  const float* Wnc = (const float*)d_in[17];
  const float* bnc = (const float*)d_in[18];
  const float* Wg1 = (const float*)d_in[19];
  const float* bg1 = (const float*)d_in[20];
  const float* Wgc = (const float*)d_in[21];
  const float* bgc = (const float*)d_in[22];
  const int* src = (const int*)d_in[23];
  const int* dst = (const int*)d_in[24];
  const int* gid = (const int*)d_in[25];

  const int n = NN, e = NE;

  // ---- workspace carve (256B aligned) ----
  char* w = (char*)d_ws;
  auto alloc = [&](size_t bytes) -> void* {
    void* p = (void*)w;
    w += (bytes + 255) & ~(size_t)255;
    return p;
  };
  float* Hb = (float*)alloc((size_t)n * HD * 4);
  float* S1 = (float*)alloc((size_t)n * HD * 4);
  float* S2 = (float*)alloc((size_t)n * HD * 4);
  int* csr_src = (int*)alloc((size_t)e * 4);
  int* row_ptr = (int*)alloc((size_t)(n + 1) * 4);
  int* cursor = (int*)alloc((size_t)n * 4);
  int* outcnt = (int*)alloc((size_t)n * 4);
  int* incnt = (int*)alloc((size_t)n * 4);
  int* excl = (int*)alloc((size_t)n * 4);
  int* bsum = (int*)alloc(256 * 4);
  float* rs_out = (float*)alloc((size_t)n * 4);
  float* rs_in = (float*)alloc((size_t)n * 4);
  float* sums = (float*)alloc(256 * 4);
  float* bnp = (float*)alloc(256 * 4);

  const int EB = (e + 255) / 256;        // 3125
  const int NB = (n + 255) / 256;        // 196
  const int MMB = (n + 31) / 32;         // 1563
  const int AGB = (n + 3) / 4;           // 12500
  const int ELB = ((n * HD / 2) + 255) / 256;  // 12500
  const int NOB = (n * 8 + 255) / 256;   // 1563

  // ---- degrees + CSR build (per call; deterministic inputs) ----
  hipMemsetAsync(outcnt, 0, (size_t)n * 4, stream);
  hipMemsetAsync(incnt, 0, (size_t)n * 4, stream);
  deg_kernel<<<EB, 256, 0, stream>>>(src, dst, outcnt, incnt, e);
  rs_kernel<<<NB, 256, 0, stream>>>(outcnt, incnt, rs_out, rs_in, n);
  scan1_kernel<<<NB, 256, 0, stream>>>(incnt, excl, bsum, n);
  scan2_kernel<<<1, 256, 0, stream>>>(bsum, NB);
  scan3_kernel<<<NB, 256, 0, stream>>>(excl, bsum, row_ptr, cursor, n, e);
  fill_kernel<<<EB, 256, 0, stream>>>(src, dst, cursor, csr_src, e);

  // ---- layer 1: h = lrelu(bn(gconv(node_feat, W1, b1))) ----
  mm128_kernel<<<MMB, 256, 0, stream>>>(node_feat, W1, rs_out, nullptr, nullptr, S1, n);
  agg_kernel<<<AGB, 256, 0, stream>>>(S1, row_ptr, csr_src, rs_in, b1, S2, n, 0);
  hipMemsetAsync(sums, 0, 256 * 4, stream);
  stats_kernel<<<256, 256, 0, stream>>>(S2, n, sums);
  bnfin_kernel<<<1, 128, 0, stream>>>(sums, g1, be1, bnp, (float)n);
  bnapply_kernel<<<ELB, 256, 0, stream>>>(S2, bnp, Hb, n);

  // ---- layer 2: h = lrelu(bn(gconv(h, W2, b2))) ----
  mm128_kernel<<<MMB, 256, 0, stream>>>(Hb, W2, rs_out, nullptr, nullptr, S1, n);
  agg_kernel<<<AGB, 256, 0, stream>>>(S1, row_ptr, csr_src, rs_in, b2, S2, n, 0);
  hipMemsetAsync(sums, 0, 256 * 4, stream);
  stats_kernel<<<256, 256, 0, stream>>>(S2, n, sums);
  bnfin_kernel<<<1, 128, 0, stream>>>(sums, g2, be2, bnp, (float)n);
  bnapply_kernel<<<ELB, 256, 0, stream>>>(S2, bnp, Hb, n);

  // ---- layer 3: hn = lrelu(gconv(h, Wn1, b_nn1)) ----
  mm128_kernel<<<MMB, 256, 0, stream>>>(Hb, Wn1, rs_out, nullptr, nullptr, S1, n);
  agg_kernel<<<AGB, 256, 0, stream>>>(S1, row_ptr, csr_src, rs_in, bn1, S2, n, 1);

  // ---- layer 4: hn = lrelu(gconv(hn, Wn2, b_nn2)) ----
  mm128_kernel<<<MMB, 256, 0, stream>>>(S2, Wn2, rs_out, nullptr, nullptr, S1, n);
  agg_kernel<<<AGB, 256, 0, stream>>>(S1, row_ptr, csr_src, rs_in, bn2, S2, n, 1);

  // ---- node_out = hn @ Wnc + b_nc ----
  nodeout_kernel<<<NOB, 256, 0, stream>>>(S2, Wnc, bnc, (float*)d_out, n);

  // ---- layer 5: hg = lrelu(gconv([h|nodetype], Wg1, b_g1)) via rank-1 fold ----
  mm128_kernel<<<MMB, 256, 0, stream>>>(Hb, Wg1, rs_out, nodetype, Wg1 + HD * HD, S1, n);
  agg_kernel<<<AGB, 256, 0, stream>>>(S1, row_ptr, csr_src, rs_in, bg1, S2, n, 1);

  // ---- per-graph mean + graph_out (sorted gid -> contiguous ranges, no atomics) ----
  gmean_kernel<<<64, 256, 0, stream>>>(S2, gid, Wgc, bgc, (float*)d_out + (size_t)n * 8, n);
}

// Round 3
// 880.071 us; speedup vs baseline: 1.8384x; 1.5359x over previous
//
#include <hip/hip_runtime.h>
#include <cstdint>
#include <cstddef>

#define NN 50000
#define NE 800000
#define HD 128

typedef __attribute__((ext_vector_type(8))) short bf16x8;
typedef __attribute__((ext_vector_type(4))) float f32x4;

__device__ inline unsigned short f2bf(float x) {
  unsigned u = __float_as_uint(x);
  u += 0x7FFF + ((u >> 16) & 1);  // round-to-nearest-even
  return (unsigned short)(u >> 16);
}
__device__ inline float bf2f(unsigned short h) { return __uint_as_float((unsigned)h << 16); }

// ---------------- degree histogram ----------------
__global__ __launch_bounds__(256) void deg_kernel(const int* __restrict__ src, const int* __restrict__ dst,
                                                  int* __restrict__ outcnt, int* __restrict__ incnt, int e) {
  int i = blockIdx.x * 256 + threadIdx.x;
  if (i < e) {
    atomicAdd(&outcnt[src[i]], 1);
    atomicAdd(&incnt[dst[i]], 1);
  }
}

__global__ __launch_bounds__(256) void rs_kernel(const int* __restrict__ outcnt, const int* __restrict__ incnt,
                                                 float* __restrict__ rs_out, float* __restrict__ rs_in, int n) {
  int i = blockIdx.x * 256 + threadIdx.x;
  if (i < n) {
    int oc = outcnt[i] > 1 ? outcnt[i] : 1;
    int ic = incnt[i] > 1 ? incnt[i] : 1;
    rs_out[i] = rsqrtf((float)oc);
    rs_in[i] = rsqrtf((float)ic);
  }
}

// ---------------- exclusive scan (3-kernel) ----------------
__global__ __launch_bounds__(256) void scan1_kernel(const int* __restrict__ cnt, int* __restrict__ excl,
                                                    int* __restrict__ bsum, int n) {
  __shared__ int sh[256];
  int i = blockIdx.x * 256 + threadIdx.x;
  int v = (i < n) ? cnt[i] : 0;
  sh[threadIdx.x] = v;
  __syncthreads();
  for (int off = 1; off < 256; off <<= 1) {
    int x = (threadIdx.x >= off) ? sh[threadIdx.x - off] : 0;
    __syncthreads();
    sh[threadIdx.x] += x;
    __syncthreads();
  }
  if (i < n) excl[i] = sh[threadIdx.x] - v;
  if (threadIdx.x == 255) bsum[blockIdx.x] = sh[255];
}

__global__ __launch_bounds__(256) void scan2_kernel(int* __restrict__ bsum, int nb) {
  __shared__ int sh[256];
  int v = (threadIdx.x < nb) ? bsum[threadIdx.x] : 0;
  sh[threadIdx.x] = v;
  __syncthreads();
  for (int off = 1; off < 256; off <<= 1) {
    int x = (threadIdx.x >= off) ? sh[threadIdx.x - off] : 0;
    __syncthreads();
    sh[threadIdx.x] += x;
    __syncthreads();
  }
  if (threadIdx.x < nb) bsum[threadIdx.x] = sh[threadIdx.x] - v;
}

__global__ __launch_bounds__(256) void scan3_kernel(const int* __restrict__ excl, const int* __restrict__ bsum,
                                                    int* __restrict__ row_ptr, int* __restrict__ cursor,
                                                    int n, int e) {
  int i = blockIdx.x * 256 + threadIdx.x;
  if (i < n) {
    int v = excl[i] + bsum[blockIdx.x];
    row_ptr[i] = v;
    cursor[i] = v;
  }
  if (i == 0) row_ptr[n] = e;
}

__global__ __launch_bounds__(256) void fill_kernel(const int* __restrict__ src, const int* __restrict__ dst,
                                                   int* __restrict__ cursor, int* __restrict__ csr_src, int e) {
  int i = blockIdx.x * 256 + threadIdx.x;
  if (i < e) {
    int pos = atomicAdd(&cursor[dst[i]], 1);
    csr_src[pos] = src[i];
  }
}

// ---------------- weight pack: f32 [128][128] -> hi/lo bf16 in MFMA B-fragment order ----------------
// frag f = ct*4+ks; lane l holds B[k=ks*32+(l>>4)*8+j][col=ct*16+(l&15)], j=0..7 contiguous.
__global__ __launch_bounds__(256) void convw_kernel(const float* __restrict__ W1, const float* __restrict__ W2,
                                                    const float* __restrict__ Wn1, const float* __restrict__ Wn2,
                                                    const float* __restrict__ Wg1, unsigned short* __restrict__ Wp) {
  const float* Ws[5] = {W1, W2, Wn1, Wn2, Wg1};
  const float* W = Ws[blockIdx.x];
  unsigned short* hi = Wp + (size_t)blockIdx.x * 32768;
  unsigned short* lo = hi + 16384;
  for (int s = threadIdx.x; s < 2048; s += 256) {
    int f = s >> 6, lane = s & 63;
    int ct = f >> 2, ks = f & 3;
    int col = ct * 16 + (lane & 15);
    int k0 = ks * 32 + ((lane >> 4) << 3);
    for (int j = 0; j < 8; j++) {
      float v = W[(k0 + j) * HD + col];
      unsigned short h = f2bf(v);
      hi[s * 8 + j] = h;
      lo[s * 8 + j] = f2bf(v - bf2f(h));
    }
  }
}

// ---------------- f32 -> bf16 hi/lo split (for node_feat) ----------------
__global__ __launch_bounds__(256) void conva_kernel(const float* __restrict__ X, unsigned short* __restrict__ hi,
                                                    unsigned short* __restrict__ lo, int total4) {
  int i = blockIdx.x * 256 + threadIdx.x;
  if (i >= total4) return;
  float4 v = reinterpret_cast<const float4*>(X)[i];
  ushort4 h, l;
  h.x = f2bf(v.x); l.x = f2bf(v.x - bf2f(h.x));
  h.y = f2bf(v.y); l.y = f2bf(v.y - bf2f(h.y));
  h.z = f2bf(v.z); l.z = f2bf(v.z - bf2f(h.z));
  h.w = f2bf(v.w); l.w = f2bf(v.w - bf2f(h.w));
  reinterpret_cast<ushort4*>(hi)[i] = h;
  reinterpret_cast<ushort4*>(lo)[i] = l;
}

// ---------------- MFMA GEMM: C[r][c] = (sum_k A[r][k]*W[k][c] (+ evec[r]*erow[c])) * rs[r] ----------------
// Split-bf16: A = Ahi+Alo, W = Whi+Wlo; acc += Ahi*Whi + Alo*Whi + Ahi*Wlo (lo*lo dropped, ~2^-18)
// Wave tile: 16 rows x 128 cols; block = 4 waves = 64 rows. No LDS -> no occupancy cap.
__global__ __launch_bounds__(256) void mmfma_kernel(const unsigned short* __restrict__ Ahi,
                                                    const unsigned short* __restrict__ Alo,
                                                    const unsigned short* __restrict__ Wp,
                                                    const float* __restrict__ rs,
                                                    const float* __restrict__ evec,
                                                    const float* __restrict__ erow,
                                                    float* __restrict__ C, int n) {
  const int lane = threadIdx.x & 63;
  const int wv = threadIdx.x >> 6;
  const int rbase = (blockIdx.x * 4 + wv) * 16;
  if (rbase >= n) return;
  const int rA = min(rbase + (lane & 15), n - 1);
  const int koff = (lane >> 4) << 3;
  const unsigned short* wlo = Wp + 16384;
  f32x4 acc[8];
#pragma unroll
  for (int t = 0; t < 8; t++) acc[t] = (f32x4){0.f, 0.f, 0.f, 0.f};
#pragma unroll
  for (int ks = 0; ks < 4; ks++) {
    size_t aoff = (size_t)rA * HD + ks * 32 + koff;
    bf16x8 ah = *reinterpret_cast<const bf16x8*>(Ahi + aoff);
    bf16x8 al = *reinterpret_cast<const bf16x8*>(Alo + aoff);
#pragma unroll
    for (int ct = 0; ct < 8; ct++) {
      int fo = ((ct * 4 + ks) * 64 + lane) * 8;
      bf16x8 bh = *reinterpret_cast<const bf16x8*>(Wp + fo);
      bf16x8 bl = *reinterpret_cast<const bf16x8*>(wlo + fo);
      acc[ct] = __builtin_amdgcn_mfma_f32_16x16x32_bf16(ah, bh, acc[ct], 0, 0, 0);
      acc[ct] = __builtin_amdgcn_mfma_f32_16x16x32_bf16(al, bh, acc[ct], 0, 0, 0);
      acc[ct] = __builtin_amdgcn_mfma_f32_16x16x32_bf16(ah, bl, acc[ct], 0, 0, 0);
    }
  }
  // epilogue: C/D layout col=lane&15, row=(lane>>4)*4+reg  [guide-verified m89/m91]
  const int r0 = rbase + ((lane >> 4) << 2);
  const int cbase = lane & 15;
#pragma unroll
  for (int i = 0; i < 4; i++) {
    int r = r0 + i;
    if (r < n) {
      float rsv = rs[r];
      float ev = (evec != nullptr) ? evec[r] : 0.f;
      float* crow = C + (size_t)r * HD + cbase;
#pragma unroll
      for (int ct = 0; ct < 8; ct++) {
        float v = acc[ct][i];
        if (evec != nullptr) v = fmaf(ev, erow[ct * 16 + cbase], v);
        crow[ct * 16] = v * rsv;
      }
    }
  }
}

// ---------------- pull-mode normalized aggregation (one wave per dst node) ----------------
// out[d] = rs_in[d] * sum_{e in CSR[d]} Ys[src_e] + bias  (optional lrelu; optional bf16 hi/lo split output)
__global__ __launch_bounds__(256) void agg_kernel(const float* __restrict__ Ys, const int* __restrict__ row_ptr,
                                                  const int* __restrict__ csr_src, const float* __restrict__ rs_in,
                                                  const float* __restrict__ bias, float* __restrict__ out,
                                                  unsigned short* __restrict__ ohi, unsigned short* __restrict__ olo,
                                                  int n, int do_lrelu) {
  int wave = threadIdx.x >> 6;
  int lane = threadIdx.x & 63;
  int node = blockIdx.x * 4 + wave;
  if (node >= n) return;
  int beg = row_ptr[node], end = row_ptr[node + 1];
  float ax = 0.f, ay = 0.f;
  for (int e = beg; e < end; ++e) {
    int s = csr_src[e];
    float2 v = reinterpret_cast<const float2*>(Ys + (size_t)s * HD)[lane];
    ax += v.x;
    ay += v.y;
  }
  float ri = rs_in[node];
  float2 b = reinterpret_cast<const float2*>(bias)[lane];
  float ox = fmaf(ax, ri, b.x);
  float oy = fmaf(ay, ri, b.y);
  if (do_lrelu) {
    ox = ox >= 0.f ? ox : 0.01f * ox;
    oy = oy >= 0.f ? oy : 0.01f * oy;
  }
  if (ohi != nullptr) {
    ushort2 h, l;
    h.x = f2bf(ox); l.x = f2bf(ox - bf2f(h.x));
    h.y = f2bf(oy); l.y = f2bf(oy - bf2f(h.y));
    reinterpret_cast<ushort2*>(ohi)[(size_t)node * 64 + lane] = h;
    reinterpret_cast<ushort2*>(olo)[(size_t)node * 64 + lane] = l;
  } else {
    reinterpret_cast<float2*>(out + (size_t)node * HD)[lane] = make_float2(ox, oy);
  }
}

// ---------------- BN statistics (column sums / sumsq) ----------------
__global__ __launch_bounds__(256) void stats_kernel(const float* __restrict__ Z, int n, float* __restrict__ sums) {
  int c = threadIdx.x & 127;
  int half = threadIdx.x >> 7;
  float s = 0.f, s2 = 0.f;
  for (int r = blockIdx.x * 2 + half; r < n; r += gridDim.x * 2) {
    float v = Z[(size_t)r * HD + c];
    s += v;
    s2 = fmaf(v, v, s2);
  }
  __shared__ float ls[512];
  ls[threadIdx.x] = s;
  ls[256 + threadIdx.x] = s2;
  __syncthreads();
  if (threadIdx.x < 128) {
    atomicAdd(&sums[c], ls[threadIdx.x] + ls[threadIdx.x + 128]);
    atomicAdd(&sums[128 + c], ls[256 + threadIdx.x] + ls[256 + threadIdx.x + 128]);
  }
}

__global__ void bnfin_kernel(const float* __restrict__ sums, const float* __restrict__ gamma,
                             const float* __restrict__ beta, float* __restrict__ bnp, float n) {
  int c = threadIdx.x;  // 128
  float mu = sums[c] / n;
  float var = sums[128 + c] / n - mu * mu;
  if (var < 0.f) var = 0.f;
  float sc = gamma[c] * rsqrtf(var + 1e-5f);
  bnp[c] = sc;
  bnp[128 + c] = fmaf(-mu, sc, beta[c]);
}

// BN-apply + lrelu, emitting bf16 hi/lo split directly (consumed only by MFMA matmuls)
__global__ __launch_bounds__(256) void bnapply_kernel(const float* __restrict__ Z, const float* __restrict__ bnp,
                                                      unsigned short* __restrict__ hi, unsigned short* __restrict__ lo,
                                                      int n) {
  int i = blockIdx.x * 256 + threadIdx.x;  // per float4
  if (i >= n * HD / 4) return;
  float4 v = reinterpret_cast<const float4*>(Z)[i];
  int c = (i * 4) & 127;
  float o[4] = {v.x, v.y, v.z, v.w};
  ushort4 h, l;
  unsigned short* hp = (unsigned short*)&h;
  unsigned short* lp = (unsigned short*)&l;
#pragma unroll
  for (int j = 0; j < 4; j++) {
    float a = fmaf(o[j], bnp[c + j], bnp[128 + c + j]);
    a = a >= 0.f ? a : 0.01f * a;
    hp[j] = f2bf(a);
    lp[j] = f2bf(a - bf2f(hp[j]));
  }
  reinterpret_cast<ushort4*>(hi)[i] = h;
  reinterpret_cast<ushort4*>(lo)[i] = l;
}

// ---------------- node_out = X@Wnc + b_nc  ([n,128]@[128,8]) ----------------
__global__ __launch_bounds__(256) void nodeout_kernel(const float* __restrict__ X, const float* __restrict__ Wnc,
                                                      const float* __restrict__ b, float* __restrict__ out, int n) {
  __shared__ float Wl[HD * 8];
  __shared__ float bl[8];
  for (int i = threadIdx.x; i < HD * 8; i += 256) Wl[i] = Wnc[i];
  if (threadIdx.x < 8) bl[threadIdx.x] = b[threadIdx.x];
  __syncthreads();
  int t = blockIdx.x * 256 + threadIdx.x;
  int r = t >> 3, c = t & 7;
  if (r >= n) return;
  const float* x = X + (size_t)r * HD;
  float acc = bl[c];
  for (int k = 0; k < HD; k += 4) {
    float4 a = *reinterpret_cast<const float4*>(x + k);
    acc = fmaf(a.x, Wl[k * 8 + c], acc);
    acc = fmaf(a.y, Wl[(k + 1) * 8 + c], acc);
    acc = fmaf(a.z, Wl[(k + 2) * 8 + c], acc);
    acc = fmaf(a.w, Wl[(k + 3) * 8 + c], acc);
  }
  out[(size_t)r * 8 + c] = acc;
}

// ---------------- per-graph mean + graph_out (gid is SORTED: contiguous ranges) ----------------
__global__ __launch_bounds__(256) void gmean_kernel(const float* __restrict__ HG, const int* __restrict__ gid,
                                                    const float* __restrict__ Wgc, const float* __restrict__ bgc,
                                                    float* __restrict__ out, int n) {
  const int g = blockIdx.x;  // 64 blocks
  int lo = 0, hi = n;
  while (lo < hi) { int mid = (lo + hi) >> 1; if (gid[mid] < g) lo = mid + 1; else hi = mid; }
  const int beg = lo;
  lo = 0; hi = n;
  while (lo < hi) { int mid = (lo + hi) >> 1; if (gid[mid] < g + 1) lo = mid + 1; else hi = mid; }
  const int end = lo;

  const int c = threadIdx.x & 127;
  const int half = threadIdx.x >> 7;
  float s = 0.f;
  for (int r = beg + half; r < end; r += 2)
    s += HG[(size_t)r * HD + c];

  __shared__ float sh[256];
  sh[threadIdx.x] = s;
  __syncthreads();
  float cntf = (float)(end - beg);
  float inv = 1.f / (cntf > 1.f ? cntf : 1.f);
  if (threadIdx.x < 128) sh[threadIdx.x] = (sh[threadIdx.x] + sh[threadIdx.x + 128]) * inv;
  __syncthreads();
  if (threadIdx.x < 4) {
    float acc = bgc[threadIdx.x];
    for (int k = 0; k < HD; k++) acc = fmaf(sh[k], Wgc[k * 4 + threadIdx.x], acc);
    out[g * 4 + threadIdx.x] = acc;
  }
}

extern "C" void kernel_launch(void* const* d_in, const int* in_sizes, int n_in,
                              void* d_out, int out_size, void* d_ws, size_t ws_size,
                              hipStream_t stream) {
  const float* node_feat = (const float*)d_in[0];
  const float* nodetype = (const float*)d_in[1];
  // d_in[2] edge_feat: dead branch, unused
  const float* W1 = (const float*)d_in[3];
  const float* b1 = (const float*)d_in[4];
  const float* g1 = (const float*)d_in[5];
  const float* be1 = (const float*)d_in[6];
  const float* W2 = (const float*)d_in[7];
  const float* b2 = (const float*)d_in[8];
  const float* g2 = (const float*)d_in[9];
  const float* be2 = (const float*)d_in[10];
  // 11 We, 12 b_e: dead
  const float* Wn1 = (const float*)d_in[13];
  const float* bn1 = (const float*)d_in[14];
  const float* Wn2 = (const float*)d_in[15];
  const float* bn2 = (const float*)d_in[16];
  const float* Wnc = (const float*)d_in[17];
  const float* bnc = (const float*)d_in[18];
  const float* Wg1 = (const float*)d_in[19];
  const float* bg1 = (const float*)d_in[20];
  const float* Wgc = (const float*)d_in[21];
  const float* bgc = (const float*)d_in[22];
  const int* src = (const int*)d_in[23];
  const int* dst = (const int*)d_in[24];
  const int* gid = (const int*)d_in[25];

  const int n = NN, e = NE;

  // ---- workspace carve (256B aligned) ----
  char* w = (char*)d_ws;
  auto alloc = [&](size_t bytes) -> void* {
    void* p = (void*)w;
    w += (bytes + 255) & ~(size_t)255;
    return p;
  };
  unsigned short* HBhi = (unsigned short*)alloc((size_t)n * HD * 2);  // h (post-BN) bf16-hi
  unsigned short* HBlo = (unsigned short*)alloc((size_t)n * HD * 2);  // h bf16-lo
  float* S1 = (float*)alloc((size_t)n * HD * 4);                      // mm output (pre-agg)
  float* S2 = (float*)alloc((size_t)n * HD * 4);                      // agg output / aliased region
  // aliases inside S2 region (live ranges disjoint with S2-f32 use):
  unsigned short* NFhi = (unsigned short*)S2;                 // node_feat split (dead after L1 mm)
  unsigned short* NFlo = NFhi + (size_t)n * HD;
  unsigned short* XHhi = (unsigned short*)S2;                 // layer-3 agg out (dead after L4 mm)
  unsigned short* XHlo = XHhi + (size_t)n * HD;
  int* csr_src = (int*)alloc((size_t)e * 4);
  int* row_ptr = (int*)alloc((size_t)(n + 1) * 4);
  int* cursor = (int*)alloc((size_t)n * 4);
  int* outcnt = (int*)alloc((size_t)n * 4);
  int* incnt = (int*)alloc((size_t)n * 4);
  int* excl = (int*)alloc((size_t)n * 4);
  int* bsum = (int*)alloc(256 * 4);
  float* rs_out = (float*)alloc((size_t)n * 4);
  float* rs_in = (float*)alloc((size_t)n * 4);
  float* sums = (float*)alloc(256 * 4);
  float* bnp = (float*)alloc(256 * 4);
  unsigned short* Wp = (unsigned short*)alloc(5 * 32768 * 2);  // 5 layers x (16K hi + 16K lo) ushorts

  const int EB = (e + 255) / 256;
  const int NB = (n + 255) / 256;
  const int MMB = (n + 63) / 64;               // 782 blocks, 64 rows each
  const int AGB = (n + 3) / 4;
  const int CVB = ((n * HD / 4) + 255) / 256;  // 6250
  const int NOB = (n * 8 + 255) / 256;

  // ---- weight pack + node_feat split (independent of CSR chain) ----
  convw_kernel<<<5, 256, 0, stream>>>(W1, W2, Wn1, Wn2, Wg1, Wp);
  conva_kernel<<<CVB, 256, 0, stream>>>(node_feat, NFhi, NFlo, n * HD / 4);

  // ---- degrees + CSR build ----
  hipMemsetAsync(outcnt, 0, (size_t)n * 4, stream);
  hipMemsetAsync(incnt, 0, (size_t)n * 4, stream);
  deg_kernel<<<EB, 256, 0, stream>>>(src, dst, outcnt, incnt, e);
  rs_kernel<<<NB, 256, 0, stream>>>(outcnt, incnt, rs_out, rs_in, n);
  scan1_kernel<<<NB, 256, 0, stream>>>(incnt, excl, bsum, n);
  scan2_kernel<<<1, 256, 0, stream>>>(bsum, NB);
  scan3_kernel<<<NB, 256, 0, stream>>>(excl, bsum, row_ptr, cursor, n, e);
  fill_kernel<<<EB, 256, 0, stream>>>(src, dst, cursor, csr_src, e);

  // ---- layer 1: h = lrelu(bn(gconv(node_feat, W1, b1))) ----
  mmfma_kernel<<<MMB, 256, 0, stream>>>(NFhi, NFlo, Wp + 0 * 32768, rs_out, nullptr, nullptr, S1, n);
  agg_kernel<<<AGB, 256, 0, stream>>>(S1, row_ptr, csr_src, rs_in, b1, S2, nullptr, nullptr, n, 0);
  hipMemsetAsync(sums, 0, 256 * 4, stream);
  stats_kernel<<<256, 256, 0, stream>>>(S2, n, sums);
  bnfin_kernel<<<1, 128, 0, stream>>>(sums, g1, be1, bnp, (float)n);
  bnapply_kernel<<<CVB, 256, 0, stream>>>(S2, bnp, HBhi, HBlo, n);

  // ---- layer 2: h = lrelu(bn(gconv(h, W2, b2))) ----
  mmfma_kernel<<<MMB, 256, 0, stream>>>(HBhi, HBlo, Wp + 1 * 32768, rs_out, nullptr, nullptr, S1, n);
  agg_kernel<<<AGB, 256, 0, stream>>>(S1, row_ptr, csr_src, rs_in, b2, S2, nullptr, nullptr, n, 0);
  hipMemsetAsync(sums, 0, 256 * 4, stream);
  stats_kernel<<<256, 256, 0, stream>>>(S2, n, sums);
  bnfin_kernel<<<1, 128, 0, stream>>>(sums, g2, be2, bnp, (float)n);
  bnapply_kernel<<<CVB, 256, 0, stream>>>(S2, bnp, HBhi, HBlo, n);

  // ---- layer 3: hn = lrelu(gconv(h, Wn1, b_nn1)) -> bf16 split (feeds only L4 mm) ----
  mmfma_kernel<<<MMB, 256, 0, stream>>>(HBhi, HBlo, Wp + 2 * 32768, rs_out, nullptr, nullptr, S1, n);
  agg_kernel<<<AGB, 256, 0, stream>>>(S1, row_ptr, csr_src, rs_in, bn1, nullptr, XHhi, XHlo, n, 1);

  // ---- layer 4: hn = lrelu(gconv(hn, Wn2, b_nn2)) ----
  mmfma_kernel<<<MMB, 256, 0, stream>>>(XHhi, XHlo, Wp + 3 * 32768, rs_out, nullptr, nullptr, S1, n);
  agg_kernel<<<AGB, 256, 0, stream>>>(S1, row_ptr, csr_src, rs_in, bn2, S2, nullptr, nullptr, n, 1);

  // ---- node_out = hn @ Wnc + b_nc ----
  nodeout_kernel<<<NOB, 256, 0, stream>>>(S2, Wnc, bnc, (float*)d_out, n);

  // ---- layer 5: hg = lrelu(gconv([h|nodetype], Wg1, b_g1)) via rank-1 fold ----
  mmfma_kernel<<<MMB, 256, 0, stream>>>(HBhi, HBlo, Wp + 4 * 32768, rs_out, nodetype, Wg1 + HD * HD, S1, n);
  agg_kernel<<<AGB, 256, 0, stream>>>(S1, row_ptr, csr_src, rs_in, bg1, S2, nullptr, nullptr, n, 1);

  // ---- per-graph mean + graph_out ----
  gmean_kernel<<<64, 256, 0, stream>>>(S2, gid, Wgc, bgc, (float*)d_out + (size_t)n * 8, n);
}

// Round 4
// 647.340 us; speedup vs baseline: 2.4994x; 1.3595x over previous
//
#include <hip/hip_runtime.h>
#include <cstdint>
#include <cstddef>

#define NN 50000
#define NE 800000
#define HD 128
#define GK 16  // chunk-blocks per graph in gpart

typedef __attribute__((ext_vector_type(8))) short bf16x8;
typedef __attribute__((ext_vector_type(4))) float f32x4;

__device__ inline unsigned short f2bf(float x) {
  unsigned u = __float_as_uint(x);
  u += 0x7FFF + ((u >> 16) & 1);  // round-to-nearest-even
  return (unsigned short)(u >> 16);
}
__device__ inline float bf2f(unsigned short h) { return __uint_as_float((unsigned)h << 16); }

// ---------------- degree histogram ----------------
__global__ __launch_bounds__(256) void deg_kernel(const int* __restrict__ src, const int* __restrict__ dst,
                                                  int* __restrict__ outcnt, int* __restrict__ incnt, int e) {
  int i = blockIdx.x * 256 + threadIdx.x;
  if (i < e) {
    atomicAdd(&outcnt[src[i]], 1);
    atomicAdd(&incnt[dst[i]], 1);
  }
}

__global__ __launch_bounds__(256) void rs_kernel(const int* __restrict__ outcnt, const int* __restrict__ incnt,
                                                 float* __restrict__ rs_out, float* __restrict__ rs_in, int n) {
  int i = blockIdx.x * 256 + threadIdx.x;
  if (i < n) {
    int oc = outcnt[i] > 1 ? outcnt[i] : 1;
    int ic = incnt[i] > 1 ? incnt[i] : 1;
    rs_out[i] = rsqrtf((float)oc);
    rs_in[i] = rsqrtf((float)ic);
  }
}

// ---------------- exclusive scan (3-kernel) ----------------
__global__ __launch_bounds__(256) void scan1_kernel(const int* __restrict__ cnt, int* __restrict__ excl,
                                                    int* __restrict__ bsum, int n) {
  __shared__ int sh[256];
  int i = blockIdx.x * 256 + threadIdx.x;
  int v = (i < n) ? cnt[i] : 0;
  sh[threadIdx.x] = v;
  __syncthreads();
  for (int off = 1; off < 256; off <<= 1) {
    int x = (threadIdx.x >= off) ? sh[threadIdx.x - off] : 0;
    __syncthreads();
    sh[threadIdx.x] += x;
    __syncthreads();
  }
  if (i < n) excl[i] = sh[threadIdx.x] - v;
  if (threadIdx.x == 255) bsum[blockIdx.x] = sh[255];
}

__global__ __launch_bounds__(256) void scan2_kernel(int* __restrict__ bsum, int nb) {
  __shared__ int sh[256];
  int v = (threadIdx.x < nb) ? bsum[threadIdx.x] : 0;
  sh[threadIdx.x] = v;
  __syncthreads();
  for (int off = 1; off < 256; off <<= 1) {
    int x = (threadIdx.x >= off) ? sh[threadIdx.x - off] : 0;
    __syncthreads();
    sh[threadIdx.x] += x;
    __syncthreads();
  }
  if (threadIdx.x < nb) bsum[threadIdx.x] = sh[threadIdx.x] - v;
}

__global__ __launch_bounds__(256) void scan3_kernel(const int* __restrict__ excl, const int* __restrict__ bsum,
                                                    int* __restrict__ row_ptr, int* __restrict__ cursor,
                                                    int n, int e) {
  int i = blockIdx.x * 256 + threadIdx.x;
  if (i < n) {
    int v = excl[i] + bsum[blockIdx.x];
    row_ptr[i] = v;
    cursor[i] = v;
  }
  if (i == 0) row_ptr[n] = e;
}

__global__ __launch_bounds__(256) void fill_kernel(const int* __restrict__ src, const int* __restrict__ dst,
                                                   int* __restrict__ cursor, int* __restrict__ csr_src, int e) {
  int i = blockIdx.x * 256 + threadIdx.x;
  if (i < e) {
    int pos = atomicAdd(&cursor[dst[i]], 1);
    csr_src[pos] = src[i];
  }
}

// ---------------- weight pack: f32 [128][128] -> hi/lo bf16 in MFMA B-fragment order ----------------
__global__ __launch_bounds__(256) void convw_kernel(const float* __restrict__ W1, const float* __restrict__ W2,
                                                    const float* __restrict__ Wn1, const float* __restrict__ Wn2,
                                                    const float* __restrict__ Wg1, unsigned short* __restrict__ Wp) {
  const float* Ws[5] = {W1, W2, Wn1, Wn2, Wg1};
  const float* W = Ws[blockIdx.x];
  unsigned short* hi = Wp + (size_t)blockIdx.x * 32768;
  unsigned short* lo = hi + 16384;
  for (int s = threadIdx.x; s < 2048; s += 256) {
    int f = s >> 6, lane = s & 63;
    int ct = f >> 2, ks = f & 3;
    int col = ct * 16 + (lane & 15);
    int k0 = ks * 32 + ((lane >> 4) << 3);
    for (int j = 0; j < 8; j++) {
      float v = W[(k0 + j) * HD + col];
      unsigned short h = f2bf(v);
      hi[s * 8 + j] = h;
      lo[s * 8 + j] = f2bf(v - bf2f(h));
    }
  }
}

// ---------------- f32 -> bf16 hi/lo split (for node_feat) ----------------
__global__ __launch_bounds__(256) void conva_kernel(const float* __restrict__ X, unsigned short* __restrict__ hi,
                                                    unsigned short* __restrict__ lo, int total4) {
  int i = blockIdx.x * 256 + threadIdx.x;
  if (i >= total4) return;
  float4 v = reinterpret_cast<const float4*>(X)[i];
  ushort4 h, l;
  h.x = f2bf(v.x); l.x = f2bf(v.x - bf2f(h.x));
  h.y = f2bf(v.y); l.y = f2bf(v.y - bf2f(h.y));
  h.z = f2bf(v.z); l.z = f2bf(v.z - bf2f(h.z));
  h.w = f2bf(v.w); l.w = f2bf(v.w - bf2f(h.w));
  reinterpret_cast<ushort4*>(hi)[i] = h;
  reinterpret_cast<ushort4*>(lo)[i] = l;
}

// ---------------- MFMA GEMM: C[r][c] = (sum_k A[r][k]*W[k][c] (+ evec[r]*erow[c])) * rs[r] ----------------
__global__ __launch_bounds__(256) void mmfma_kernel(const unsigned short* __restrict__ Ahi,
                                                    const unsigned short* __restrict__ Alo,
                                                    const unsigned short* __restrict__ Wp,
                                                    const float* __restrict__ rs,
                                                    const float* __restrict__ evec,
                                                    const float* __restrict__ erow,
                                                    float* __restrict__ C, int n) {
  const int lane = threadIdx.x & 63;
  const int wv = threadIdx.x >> 6;
  const int rbase = (blockIdx.x * 4 + wv) * 16;
  if (rbase >= n) return;
  const int rA = min(rbase + (lane & 15), n - 1);
  const int koff = (lane >> 4) << 3;
  const unsigned short* wlo = Wp + 16384;
  f32x4 acc[8];
#pragma unroll
  for (int t = 0; t < 8; t++) acc[t] = (f32x4){0.f, 0.f, 0.f, 0.f};
#pragma unroll
  for (int ks = 0; ks < 4; ks++) {
    size_t aoff = (size_t)rA * HD + ks * 32 + koff;
    bf16x8 ah = *reinterpret_cast<const bf16x8*>(Ahi + aoff);
    bf16x8 al = *reinterpret_cast<const bf16x8*>(Alo + aoff);
#pragma unroll
    for (int ct = 0; ct < 8; ct++) {
      int fo = ((ct * 4 + ks) * 64 + lane) * 8;
      bf16x8 bh = *reinterpret_cast<const bf16x8*>(Wp + fo);
      bf16x8 bl = *reinterpret_cast<const bf16x8*>(wlo + fo);
      acc[ct] = __builtin_amdgcn_mfma_f32_16x16x32_bf16(ah, bh, acc[ct], 0, 0, 0);
      acc[ct] = __builtin_amdgcn_mfma_f32_16x16x32_bf16(al, bh, acc[ct], 0, 0, 0);
      acc[ct] = __builtin_amdgcn_mfma_f32_16x16x32_bf16(ah, bl, acc[ct], 0, 0, 0);
    }
  }
  const int r0 = rbase + ((lane >> 4) << 2);
  const int cbase = lane & 15;
#pragma unroll
  for (int i = 0; i < 4; i++) {
    int r = r0 + i;
    if (r < n) {
      float rsv = rs[r];
      float ev = (evec != nullptr) ? evec[r] : 0.f;
      float* crow = C + (size_t)r * HD + cbase;
#pragma unroll
      for (int ct = 0; ct < 8; ct++) {
        float v = acc[ct][i];
        if (evec != nullptr) v = fmaf(ev, erow[ct * 16 + cbase], v);
        crow[ct * 16] = v * rsv;
      }
    }
  }
}

// ---------------- pull-mode normalized aggregation (one wave per dst node, 4-edge ILP) ----------------
__global__ __launch_bounds__(256) void agg_kernel(const float* __restrict__ Ys, const int* __restrict__ row_ptr,
                                                  const int* __restrict__ csr_src, const float* __restrict__ rs_in,
                                                  const float* __restrict__ bias, float* __restrict__ out,
                                                  unsigned short* __restrict__ ohi, unsigned short* __restrict__ olo,
                                                  int n, int do_lrelu) {
  int wave = threadIdx.x >> 6;
  int lane = threadIdx.x & 63;
  int node = blockIdx.x * 4 + wave;
  if (node >= n) return;
  int beg = row_ptr[node], end = row_ptr[node + 1];
  float ax = 0.f, ay = 0.f;
  int e = beg;
  // 4-way unroll: 4 independent row loads in flight (latency hiding)
  for (; e + 3 < end; e += 4) {
    int s0 = csr_src[e], s1 = csr_src[e + 1], s2 = csr_src[e + 2], s3 = csr_src[e + 3];
    float2 v0 = reinterpret_cast<const float2*>(Ys + (size_t)s0 * HD)[lane];
    float2 v1 = reinterpret_cast<const float2*>(Ys + (size_t)s1 * HD)[lane];
    float2 v2 = reinterpret_cast<const float2*>(Ys + (size_t)s2 * HD)[lane];
    float2 v3 = reinterpret_cast<const float2*>(Ys + (size_t)s3 * HD)[lane];
    ax += (v0.x + v1.x) + (v2.x + v3.x);
    ay += (v0.y + v1.y) + (v2.y + v3.y);
  }
  for (; e < end; ++e) {
    int s = csr_src[e];
    float2 v = reinterpret_cast<const float2*>(Ys + (size_t)s * HD)[lane];
    ax += v.x;
    ay += v.y;
  }
  float ri = rs_in[node];
  float2 b = reinterpret_cast<const float2*>(bias)[lane];
  float ox = fmaf(ax, ri, b.x);
  float oy = fmaf(ay, ri, b.y);
  if (do_lrelu) {
    ox = ox >= 0.f ? ox : 0.01f * ox;
    oy = oy >= 0.f ? oy : 0.01f * oy;
  }
  if (ohi != nullptr) {
    ushort2 h, l;
    h.x = f2bf(ox); l.x = f2bf(ox - bf2f(h.x));
    h.y = f2bf(oy); l.y = f2bf(oy - bf2f(h.y));
    reinterpret_cast<ushort2*>(ohi)[(size_t)node * 64 + lane] = h;
    reinterpret_cast<ushort2*>(olo)[(size_t)node * 64 + lane] = l;
  } else {
    reinterpret_cast<float2*>(out + (size_t)node * HD)[lane] = make_float2(ox, oy);
  }
}

// ---------------- BN statistics (column sums / sumsq) ----------------
__global__ __launch_bounds__(256) void stats_kernel(const float* __restrict__ Z, int n, float* __restrict__ sums) {
  int c = threadIdx.x & 127;
  int half = threadIdx.x >> 7;
  float s = 0.f, s2 = 0.f;
  for (int r = blockIdx.x * 2 + half; r < n; r += gridDim.x * 2) {
    float v = Z[(size_t)r * HD + c];
    s += v;
    s2 = fmaf(v, v, s2);
  }
  __shared__ float ls[512];
  ls[threadIdx.x] = s;
  ls[256 + threadIdx.x] = s2;
  __syncthreads();
  if (threadIdx.x < 128) {
    atomicAdd(&sums[c], ls[threadIdx.x] + ls[threadIdx.x + 128]);
    atomicAdd(&sums[128 + c], ls[256 + threadIdx.x] + ls[256 + threadIdx.x + 128]);
  }
}

__global__ void bnfin_kernel(const float* __restrict__ sums, const float* __restrict__ gamma,
                             const float* __restrict__ beta, float* __restrict__ bnp, float n) {
  int c = threadIdx.x;  // 128
  float mu = sums[c] / n;
  float var = sums[128 + c] / n - mu * mu;
  if (var < 0.f) var = 0.f;
  float sc = gamma[c] * rsqrtf(var + 1e-5f);
  bnp[c] = sc;
  bnp[128 + c] = fmaf(-mu, sc, beta[c]);
}

// BN-apply + lrelu, emitting bf16 hi/lo split directly
__global__ __launch_bounds__(256) void bnapply_kernel(const float* __restrict__ Z, const float* __restrict__ bnp,
                                                      unsigned short* __restrict__ hi, unsigned short* __restrict__ lo,
                                                      int n) {
  int i = blockIdx.x * 256 + threadIdx.x;  // per float4
  if (i >= n * HD / 4) return;
  float4 v = reinterpret_cast<const float4*>(Z)[i];
  int c = (i * 4) & 127;
  float o[4] = {v.x, v.y, v.z, v.w};
  ushort4 h, l;
  unsigned short* hp = (unsigned short*)&h;
  unsigned short* lp = (unsigned short*)&l;
#pragma unroll
  for (int j = 0; j < 4; j++) {
    float a = fmaf(o[j], bnp[c + j], bnp[128 + c + j]);
    a = a >= 0.f ? a : 0.01f * a;
    hp[j] = f2bf(a);
    lp[j] = f2bf(a - bf2f(hp[j]));
  }
  reinterpret_cast<ushort4*>(hi)[i] = h;
  reinterpret_cast<ushort4*>(lo)[i] = l;
}

// ---------------- node_out = X@Wnc + b_nc  ([n,128]@[128,8]) ----------------
__global__ __launch_bounds__(256) void nodeout_kernel(const float* __restrict__ X, const float* __restrict__ Wnc,
                                                      const float* __restrict__ b, float* __restrict__ out, int n) {
  __shared__ float Wl[HD * 8];
  __shared__ float bl[8];
  for (int i = threadIdx.x; i < HD * 8; i += 256) Wl[i] = Wnc[i];
  if (threadIdx.x < 8) bl[threadIdx.x] = b[threadIdx.x];
  __syncthreads();
  int t = blockIdx.x * 256 + threadIdx.x;
  int r = t >> 3, c = t & 7;
  if (r >= n) return;
  const float* x = X + (size_t)r * HD;
  float acc = bl[c];
  for (int k = 0; k < HD; k += 4) {
    float4 a = *reinterpret_cast<const float4*>(x + k);
    acc = fmaf(a.x, Wl[k * 8 + c], acc);
    acc = fmaf(a.y, Wl[(k + 1) * 8 + c], acc);
    acc = fmaf(a.z, Wl[(k + 2) * 8 + c], acc);
    acc = fmaf(a.w, Wl[(k + 3) * 8 + c], acc);
  }
  out[(size_t)r * 8 + c] = acc;
}

// ---------------- graph mean stage 1: 64 graphs x GK chunk-blocks, no atomics ----------------
__global__ __launch_bounds__(256) void gpart_kernel(const float* __restrict__ HG, const int* __restrict__ gid,
                                                    float* __restrict__ partial, int n) {
  const int g = blockIdx.x >> 4;   // GK==16
  const int j = blockIdx.x & 15;
  int lo = 0, hi = n;
  while (lo < hi) { int mid = (lo + hi) >> 1; if (gid[mid] < g) lo = mid + 1; else hi = mid; }
  const int beg = lo;
  lo = 0; hi = n;
  while (lo < hi) { int mid = (lo + hi) >> 1; if (gid[mid] < g + 1) lo = mid + 1; else hi = mid; }
  const int end = lo;
  const int len = end - beg;
  const int chunk = (len + GK - 1) / GK;
  const int r0 = beg + j * chunk;
  const int r1 = min(r0 + chunk, end);

  const int c = threadIdx.x & 127;
  const int half = threadIdx.x >> 7;
  float s = 0.f;
  for (int r = r0 + half; r < r1; r += 2)
    s += HG[(size_t)r * HD + c];  // coalesced 512B row segments

  __shared__ float sh[256];
  sh[threadIdx.x] = s;
  __syncthreads();
  if (threadIdx.x < 128)
    partial[(size_t)blockIdx.x * HD + threadIdx.x] = sh[threadIdx.x] + sh[threadIdx.x + 128];
}

// ---------------- graph mean stage 2: reduce GK partials, scale, @Wgc + bgc ----------------
__global__ __launch_bounds__(128) void gfin_kernel(const float* __restrict__ partial, const int* __restrict__ gid,
                                                   const float* __restrict__ Wgc, const float* __restrict__ bgc,
                                                   float* __restrict__ out, int n) {
  const int g = blockIdx.x;
  int lo = 0, hi = n;
  while (lo < hi) { int mid = (lo + hi) >> 1; if (gid[mid] < g) lo = mid + 1; else hi = mid; }
  const int beg = lo;
  lo = 0; hi = n;
  while (lo < hi) { int mid = (lo + hi) >> 1; if (gid[mid] < g + 1) lo = mid + 1; else hi = mid; }
  const int end = lo;
  float cntf = (float)(end - beg);
  float inv = 1.f / (cntf > 1.f ? cntf : 1.f);

  const int c = threadIdx.x;  // 128
  float s = 0.f;
#pragma unroll
  for (int j = 0; j < GK; j++) s += partial[(size_t)(g * GK + j) * HD + c];
  __shared__ float sh[128];
  sh[c] = s * inv;
  __syncthreads();
  if (c < 4) {
    float acc = bgc[c];
    for (int k = 0; k < HD; k++) acc = fmaf(sh[k], Wgc[k * 4 + c], acc);
    out[g * 4 + c] = acc;
  }
}

extern "C" void kernel_launch(void* const* d_in, const int* in_sizes, int n_in,
                              void* d_out, int out_size, void* d_ws, size_t ws_size,
                              hipStream_t stream) {
  const float* node_feat = (const float*)d_in[0];
  const float* nodetype = (const float*)d_in[1];
  // d_in[2] edge_feat: dead branch, unused
  const float* W1 = (const float*)d_in[3];
  const float* b1 = (const float*)d_in[4];
  const float* g1 = (const float*)d_in[5];
  const float* be1 = (const float*)d_in[6];
  const float* W2 = (const float*)d_in[7];
  const float* b2 = (const float*)d_in[8];
  const float* g2 = (const float*)d_in[9];
  const float* be2 = (const float*)d_in[10];
  // 11 We, 12 b_e: dead
  const float* Wn1 = (const float*)d_in[13];
  const float* bn1 = (const float*)d_in[14];
  const float* Wn2 = (const float*)d_in[15];
  const float* bn2 = (const float*)d_in[16];
  const float* Wnc = (const float*)d_in[17];
  const float* bnc = (const float*)d_in[18];
  const float* Wg1 = (const float*)d_in[19];
  const float* bg1 = (const float*)d_in[20];
  const float* Wgc = (const float*)d_in[21];
  const float* bgc = (const float*)d_in[22];
  const int* src = (const int*)d_in[23];
  const int* dst = (const int*)d_in[24];
  const int* gid = (const int*)d_in[25];

  const int n = NN, e = NE;

  // ---- workspace carve (256B aligned) ----
  char* w = (char*)d_ws;
  auto alloc = [&](size_t bytes) -> void* {
    void* p = (void*)w;
    w += (bytes + 255) & ~(size_t)255;
    return p;
  };
  unsigned short* HBhi = (unsigned short*)alloc((size_t)n * HD * 2);
  unsigned short* HBlo = (unsigned short*)alloc((size_t)n * HD * 2);
  float* S1 = (float*)alloc((size_t)n * HD * 4);
  float* S2 = (float*)alloc((size_t)n * HD * 4);
  unsigned short* NFhi = (unsigned short*)S2;  // aliases, disjoint live ranges
  unsigned short* NFlo = NFhi + (size_t)n * HD;
  unsigned short* XHhi = (unsigned short*)S2;
  unsigned short* XHlo = XHhi + (size_t)n * HD;
  int* csr_src = (int*)alloc((size_t)e * 4);
  int* row_ptr = (int*)alloc((size_t)(n + 1) * 4);
  int* cursor = (int*)alloc((size_t)n * 4);
  int* outcnt = (int*)alloc((size_t)n * 4);
  int* incnt = (int*)alloc((size_t)n * 4);
  int* excl = (int*)alloc((size_t)n * 4);
  int* bsum = (int*)alloc(256 * 4);
  float* rs_out = (float*)alloc((size_t)n * 4);
  float* rs_in = (float*)alloc((size_t)n * 4);
  float* sums = (float*)alloc(256 * 4);
  float* bnp = (float*)alloc(256 * 4);
  unsigned short* Wp = (unsigned short*)alloc(5 * 32768 * 2);
  float* partial = (float*)alloc((size_t)64 * GK * HD * 4);  // 512 KB

  const int EB = (e + 255) / 256;
  const int NB = (n + 255) / 256;
  const int MMB = (n + 63) / 64;
  const int AGB = (n + 3) / 4;
  const int CVB = ((n * HD / 4) + 255) / 256;
  const int NOB = (n * 8 + 255) / 256;

  // ---- weight pack + node_feat split ----
  convw_kernel<<<5, 256, 0, stream>>>(W1, W2, Wn1, Wn2, Wg1, Wp);
  conva_kernel<<<CVB, 256, 0, stream>>>(node_feat, NFhi, NFlo, n * HD / 4);

  // ---- degrees + CSR build ----
  hipMemsetAsync(outcnt, 0, (size_t)n * 4, stream);
  hipMemsetAsync(incnt, 0, (size_t)n * 4, stream);
  deg_kernel<<<EB, 256, 0, stream>>>(src, dst, outcnt, incnt, e);
  rs_kernel<<<NB, 256, 0, stream>>>(outcnt, incnt, rs_out, rs_in, n);
  scan1_kernel<<<NB, 256, 0, stream>>>(incnt, excl, bsum, n);
  scan2_kernel<<<1, 256, 0, stream>>>(bsum, NB);
  scan3_kernel<<<NB, 256, 0, stream>>>(excl, bsum, row_ptr, cursor, n, e);
  fill_kernel<<<EB, 256, 0, stream>>>(src, dst, cursor, csr_src, e);

  // ---- layer 1 ----
  mmfma_kernel<<<MMB, 256, 0, stream>>>(NFhi, NFlo, Wp + 0 * 32768, rs_out, nullptr, nullptr, S1, n);
  agg_kernel<<<AGB, 256, 0, stream>>>(S1, row_ptr, csr_src, rs_in, b1, S2, nullptr, nullptr, n, 0);
  hipMemsetAsync(sums, 0, 256 * 4, stream);
  stats_kernel<<<256, 256, 0, stream>>>(S2, n, sums);
  bnfin_kernel<<<1, 128, 0, stream>>>(sums, g1, be1, bnp, (float)n);
  bnapply_kernel<<<CVB, 256, 0, stream>>>(S2, bnp, HBhi, HBlo, n);

  // ---- layer 2 ----
  mmfma_kernel<<<MMB, 256, 0, stream>>>(HBhi, HBlo, Wp + 1 * 32768, rs_out, nullptr, nullptr, S1, n);
  agg_kernel<<<AGB, 256, 0, stream>>>(S1, row_ptr, csr_src, rs_in, b2, S2, nullptr, nullptr, n, 0);
  hipMemsetAsync(sums, 0, 256 * 4, stream);
  stats_kernel<<<256, 256, 0, stream>>>(S2, n, sums);
  bnfin_kernel<<<1, 128, 0, stream>>>(sums, g2, be2, bnp, (float)n);
  bnapply_kernel<<<CVB, 256, 0, stream>>>(S2, bnp, HBhi, HBlo, n);

  // ---- layer 3 ----
  mmfma_kernel<<<MMB, 256, 0, stream>>>(HBhi, HBlo, Wp + 2 * 32768, rs_out, nullptr, nullptr, S1, n);
  agg_kernel<<<AGB, 256, 0, stream>>>(S1, row_ptr, csr_src, rs_in, bn1, nullptr, XHhi, XHlo, n, 1);

  // ---- layer 4 ----
  mmfma_kernel<<<MMB, 256, 0, stream>>>(XHhi, XHlo, Wp + 3 * 32768, rs_out, nullptr, nullptr, S1, n);
  agg_kernel<<<AGB, 256, 0, stream>>>(S1, row_ptr, csr_src, rs_in, bn2, S2, nullptr, nullptr, n, 1);

  // ---- node_out ----
  nodeout_kernel<<<NOB, 256, 0, stream>>>(S2, Wnc, bnc, (float*)d_out, n);

  // ---- layer 5 (rank-1 fold of nodetype column) ----
  mmfma_kernel<<<MMB, 256, 0, stream>>>(HBhi, HBlo, Wp + 4 * 32768, rs_out, nodetype, Wg1 + HD * HD, S1, n);
  agg_kernel<<<AGB, 256, 0, stream>>>(S1, row_ptr, csr_src, rs_in, bg1, S2, nullptr, nullptr, n, 1);

  // ---- graph mean (two-stage, no atomics) + graph_out ----
  gpart_kernel<<<64 * GK, 256, 0, stream>>>(S2, gid, partial, n);
  gfin_kernel<<<64, 128, 0, stream>>>(partial, gid, Wgc, bgc, (float*)d_out + (size_t)n * 8, n);
}

// Round 5
// 557.573 us; speedup vs baseline: 2.9018x; 1.1610x over previous
//
#include <hip/hip_runtime.h>
#include <cstdint>
#include <cstddef>

#define NN 50000
#define NE 800000
#define HD 128
#define GK 16     // chunk-blocks per graph in gpart
#define HNB 64    // edge-slice blocks per (array,half) in deghist

typedef __attribute__((ext_vector_type(8))) short bf16x8;
typedef __attribute__((ext_vector_type(4))) float f32x4;

__device__ inline unsigned short f2bf(float x) {
  unsigned u = __float_as_uint(x);
  u += 0x7FFF + ((u >> 16) & 1);  // round-to-nearest-even
  return (unsigned short)(u >> 16);
}
__device__ inline float bf2f(unsigned short h) { return __uint_as_float((unsigned)h << 16); }

// ---------------- degree histogram via LDS privatization (no global atomics) ----------------
// block = (slice b, array sel, bin-half h); LDS hist of 25000 bins; partials to global.
__global__ __launch_bounds__(256) void deghist_kernel(const int* __restrict__ src, const int* __restrict__ dst,
                                                      int* __restrict__ part, int e) {
  __shared__ int hist[25000];  // 100 KB
  const int b = blockIdx.x >> 2;
  const int sel = (blockIdx.x >> 1) & 1;
  const int h = blockIdx.x & 1;
  const int* arr = sel ? dst : src;
  for (int i = threadIdx.x; i < 25000; i += 256) hist[i] = 0;
  __syncthreads();
  const int lo = h * 25000;
  const int slice = e >> 6;  // 12500
  const int base = b * slice;
  for (int i = base + threadIdx.x; i < base + slice; i += 256) {
    int v = arr[i] - lo;
    if ((unsigned)v < 25000u) atomicAdd(&hist[v], 1);  // LDS atomic: CU-local
  }
  __syncthreads();
  int* out = part + ((size_t)(sel * 2 + h) * HNB + b) * 25000;
  for (int i = threadIdx.x; i < 25000; i += 256) out[i] = hist[i];
}

// reduce partials -> incnt (for scan), rs_in, rs_out
__global__ __launch_bounds__(256) void degred_kernel(const int* __restrict__ part, int* __restrict__ incnt,
                                                     float* __restrict__ rs_out, float* __restrict__ rs_in, int n) {
  int v = blockIdx.x * 256 + threadIdx.x;
  if (v >= n) return;
  const int h = (v >= 25000) ? 1 : 0;
  const int bin = v - h * 25000;
  const int* p0 = part + ((size_t)(0 + h) * HNB) * 25000 + bin;      // sel=0 (src -> out-deg)
  const int* p1 = part + ((size_t)(2 + h) * HNB) * 25000 + bin;      // sel=1 (dst -> in-deg)
  int os = 0, is = 0;
#pragma unroll 8
  for (int b = 0; b < HNB; b++) {
    os += p0[(size_t)b * 25000];
    is += p1[(size_t)b * 25000];
  }
  incnt[v] = is;
  rs_out[v] = rsqrtf((float)(os > 1 ? os : 1));
  rs_in[v] = rsqrtf((float)(is > 1 ? is : 1));
}

// ---------------- exclusive scan (3-kernel) ----------------
__global__ __launch_bounds__(256) void scan1_kernel(const int* __restrict__ cnt, int* __restrict__ excl,
                                                    int* __restrict__ bsum, int n) {
  __shared__ int sh[256];
  int i = blockIdx.x * 256 + threadIdx.x;
  int v = (i < n) ? cnt[i] : 0;
  sh[threadIdx.x] = v;
  __syncthreads();
  for (int off = 1; off < 256; off <<= 1) {
    int x = (threadIdx.x >= off) ? sh[threadIdx.x - off] : 0;
    __syncthreads();
    sh[threadIdx.x] += x;
    __syncthreads();
  }
  if (i < n) excl[i] = sh[threadIdx.x] - v;
  if (threadIdx.x == 255) bsum[blockIdx.x] = sh[255];
}

__global__ __launch_bounds__(256) void scan2_kernel(int* __restrict__ bsum, int nb) {
  __shared__ int sh[256];
  int v = (threadIdx.x < nb) ? bsum[threadIdx.x] : 0;
  sh[threadIdx.x] = v;
  __syncthreads();
  for (int off = 1; off < 256; off <<= 1) {
    int x = (threadIdx.x >= off) ? sh[threadIdx.x - off] : 0;
    __syncthreads();
    sh[threadIdx.x] += x;
    __syncthreads();
  }
  if (threadIdx.x < nb) bsum[threadIdx.x] = sh[threadIdx.x] - v;
}

__global__ __launch_bounds__(256) void scan3_kernel(const int* __restrict__ excl, const int* __restrict__ bsum,
                                                    int* __restrict__ row_ptr, int* __restrict__ cursor,
                                                    int n, int e) {
  int i = blockIdx.x * 256 + threadIdx.x;
  if (i < n) {
    int v = excl[i] + bsum[blockIdx.x];
    row_ptr[i] = v;
    cursor[i] = v;
  }
  if (i == 0) row_ptr[n] = e;
}

__global__ __launch_bounds__(256) void fill_kernel(const int* __restrict__ src, const int* __restrict__ dst,
                                                   int* __restrict__ cursor, int* __restrict__ csr_src, int e) {
  int i = blockIdx.x * 256 + threadIdx.x;
  if (i < e) {
    int pos = atomicAdd(&cursor[dst[i]], 1);
    csr_src[pos] = src[i];
  }
}

// ---------------- weight pack: f32 [128][128] -> hi/lo bf16 in MFMA B-fragment order ----------------
__global__ __launch_bounds__(256) void convw_kernel(const float* __restrict__ W1, const float* __restrict__ W2,
                                                    const float* __restrict__ Wn1, const float* __restrict__ Wn2,
                                                    const float* __restrict__ Wg1, unsigned short* __restrict__ Wp) {
  const float* Ws[5] = {W1, W2, Wn1, Wn2, Wg1};
  const float* W = Ws[blockIdx.x];
  unsigned short* hi = Wp + (size_t)blockIdx.x * 32768;
  unsigned short* lo = hi + 16384;
  for (int s = threadIdx.x; s < 2048; s += 256) {
    int f = s >> 6, lane = s & 63;
    int ct = f >> 2, ks = f & 3;
    int col = ct * 16 + (lane & 15);
    int k0 = ks * 32 + ((lane >> 4) << 3);
    for (int j = 0; j < 8; j++) {
      float v = W[(k0 + j) * HD + col];
      unsigned short h = f2bf(v);
      hi[s * 8 + j] = h;
      lo[s * 8 + j] = f2bf(v - bf2f(h));
    }
  }
}

// ---------------- MFMA GEMM with fused input transform ----------------
// MODE 0: A is f32, split to hi/lo in-reg.  MODE 1: A is f32 pre-BN; apply x*bnp[c]+bnp[128+c],
// lrelu, then split.  C[r][c] = (sum_k A'[r][k]*W[k][c] (+ evec[r]*erow[c])) * rs[r]
template <int MODE>
__global__ __launch_bounds__(256) void mmfma_kernel(const float* __restrict__ A,
                                                    const float* __restrict__ bnp,
                                                    const unsigned short* __restrict__ Wp,
                                                    const float* __restrict__ rs,
                                                    const float* __restrict__ evec,
                                                    const float* __restrict__ erow,
                                                    float* __restrict__ C, int n) {
  const int lane = threadIdx.x & 63;
  const int wv = threadIdx.x >> 6;
  const int rbase = (blockIdx.x * 4 + wv) * 16;
  if (rbase >= n) return;
  const int rA = min(rbase + (lane & 15), n - 1);
  const int koff = (lane >> 4) << 3;
  const unsigned short* wlo = Wp + 16384;
  f32x4 acc[8];
#pragma unroll
  for (int t = 0; t < 8; t++) acc[t] = (f32x4){0.f, 0.f, 0.f, 0.f};
#pragma unroll
  for (int ks = 0; ks < 4; ks++) {
    const int c0 = ks * 32 + koff;
    const float* ap = A + (size_t)rA * HD + c0;
    float4 a0 = *reinterpret_cast<const float4*>(ap);
    float4 a1 = *reinterpret_cast<const float4*>(ap + 4);
    float av[8] = {a0.x, a0.y, a0.z, a0.w, a1.x, a1.y, a1.z, a1.w};
    if (MODE == 1) {
      float4 s0 = *reinterpret_cast<const float4*>(bnp + c0);
      float4 s1 = *reinterpret_cast<const float4*>(bnp + c0 + 4);
      float4 t0 = *reinterpret_cast<const float4*>(bnp + 128 + c0);
      float4 t1 = *reinterpret_cast<const float4*>(bnp + 128 + c0 + 4);
      float sc[8] = {s0.x, s0.y, s0.z, s0.w, s1.x, s1.y, s1.z, s1.w};
      float sf[8] = {t0.x, t0.y, t0.z, t0.w, t1.x, t1.y, t1.z, t1.w};
#pragma unroll
      for (int j = 0; j < 8; j++) {
        float x = fmaf(av[j], sc[j], sf[j]);
        av[j] = x >= 0.f ? x : 0.01f * x;
      }
    }
    bf16x8 ah, al;
#pragma unroll
    for (int j = 0; j < 8; j++) {  // static indices -> registers
      unsigned short hh = f2bf(av[j]);
      ((short*)&ah)[j] = (short)hh;
      ((short*)&al)[j] = (short)f2bf(av[j] - bf2f(hh));
    }
#pragma unroll
    for (int ct = 0; ct < 8; ct++) {
      int fo = ((ct * 4 + ks) * 64 + lane) * 8;
      bf16x8 bh = *reinterpret_cast<const bf16x8*>(Wp + fo);
      bf16x8 bl = *reinterpret_cast<const bf16x8*>(wlo + fo);
      acc[ct] = __builtin_amdgcn_mfma_f32_16x16x32_bf16(ah, bh, acc[ct], 0, 0, 0);
      acc[ct] = __builtin_amdgcn_mfma_f32_16x16x32_bf16(al, bh, acc[ct], 0, 0, 0);
      acc[ct] = __builtin_amdgcn_mfma_f32_16x16x32_bf16(ah, bl, acc[ct], 0, 0, 0);
    }
  }
  const int r0 = rbase + ((lane >> 4) << 2);
  const int cbase = lane & 15;
#pragma unroll
  for (int i = 0; i < 4; i++) {
    int r = r0 + i;
    if (r < n) {
      float rsv = rs[r];
      float ev = (evec != nullptr) ? evec[r] : 0.f;
      float* crow = C + (size_t)r * HD + cbase;
#pragma unroll
      for (int ct = 0; ct < 8; ct++) {
        float v = acc[ct][i];
        if (evec != nullptr) v = fmaf(ev, erow[ct * 16 + cbase], v);
        crow[ct * 16] = v * rsv;
      }
    }
  }
}

// ---------------- pull-mode normalized aggregation (one wave per dst node, 4-edge ILP) ----------------
__global__ __launch_bounds__(256) void agg_kernel(const float* __restrict__ Ys, const int* __restrict__ row_ptr,
                                                  const int* __restrict__ csr_src, const float* __restrict__ rs_in,
                                                  const float* __restrict__ bias, float* __restrict__ out,
                                                  int n, int do_lrelu) {
  int wave = threadIdx.x >> 6;
  int lane = threadIdx.x & 63;
  int node = blockIdx.x * 4 + wave;
  if (node >= n) return;
  int beg = row_ptr[node], end = row_ptr[node + 1];
  float ax = 0.f, ay = 0.f;
  int e = beg;
  for (; e + 3 < end; e += 4) {
    int s0 = csr_src[e], s1 = csr_src[e + 1], s2 = csr_src[e + 2], s3 = csr_src[e + 3];
    float2 v0 = reinterpret_cast<const float2*>(Ys + (size_t)s0 * HD)[lane];
    float2 v1 = reinterpret_cast<const float2*>(Ys + (size_t)s1 * HD)[lane];
    float2 v2 = reinterpret_cast<const float2*>(Ys + (size_t)s2 * HD)[lane];
    float2 v3 = reinterpret_cast<const float2*>(Ys + (size_t)s3 * HD)[lane];
    ax += (v0.x + v1.x) + (v2.x + v3.x);
    ay += (v0.y + v1.y) + (v2.y + v3.y);
  }
  for (; e < end; ++e) {
    int s = csr_src[e];
    float2 v = reinterpret_cast<const float2*>(Ys + (size_t)s * HD)[lane];
    ax += v.x;
    ay += v.y;
  }
  float ri = rs_in[node];
  float2 b = reinterpret_cast<const float2*>(bias)[lane];
  float ox = fmaf(ax, ri, b.x);
  float oy = fmaf(ay, ri, b.y);
  if (do_lrelu) {
    ox = ox >= 0.f ? ox : 0.01f * ox;
    oy = oy >= 0.f ? oy : 0.01f * oy;
  }
  reinterpret_cast<float2*>(out + (size_t)node * HD)[lane] = make_float2(ox, oy);
}

// ---------------- BN statistics (column sums / sumsq) ----------------
__global__ __launch_bounds__(256) void stats_kernel(const float* __restrict__ Z, int n, float* __restrict__ sums) {
  int c = threadIdx.x & 127;
  int half = threadIdx.x >> 7;
  float s = 0.f, s2 = 0.f;
  for (int r = blockIdx.x * 2 + half; r < n; r += gridDim.x * 2) {
    float v = Z[(size_t)r * HD + c];
    s += v;
    s2 = fmaf(v, v, s2);
  }
  __shared__ float ls[512];
  ls[threadIdx.x] = s;
  ls[256 + threadIdx.x] = s2;
  __syncthreads();
  if (threadIdx.x < 128) {
    atomicAdd(&sums[c], ls[threadIdx.x] + ls[threadIdx.x + 128]);
    atomicAdd(&sums[128 + c], ls[256 + threadIdx.x] + ls[256 + threadIdx.x + 128]);
  }
}

__global__ void bnfin_kernel(const float* __restrict__ sums, const float* __restrict__ gamma,
                             const float* __restrict__ beta, float* __restrict__ bnp, float n) {
  int c = threadIdx.x;  // 128
  float mu = sums[c] / n;
  float var = sums[128 + c] / n - mu * mu;
  if (var < 0.f) var = 0.f;
  float sc = gamma[c] * rsqrtf(var + 1e-5f);
  bnp[c] = sc;
  bnp[128 + c] = fmaf(-mu, sc, beta[c]);
}

// ---------------- node_out = X@Wnc + b_nc  ([n,128]@[128,8]) ----------------
__global__ __launch_bounds__(256) void nodeout_kernel(const float* __restrict__ X, const float* __restrict__ Wnc,
                                                      const float* __restrict__ b, float* __restrict__ out, int n) {
  __shared__ float Wl[HD * 8];
  __shared__ float bl[8];
  for (int i = threadIdx.x; i < HD * 8; i += 256) Wl[i] = Wnc[i];
  if (threadIdx.x < 8) bl[threadIdx.x] = b[threadIdx.x];
  __syncthreads();
  int t = blockIdx.x * 256 + threadIdx.x;
  int r = t >> 3, c = t & 7;
  if (r >= n) return;
  const float* x = X + (size_t)r * HD;
  float acc = bl[c];
  for (int k = 0; k < HD; k += 4) {
    float4 a = *reinterpret_cast<const float4*>(x + k);
    acc = fmaf(a.x, Wl[k * 8 + c], acc);
    acc = fmaf(a.y, Wl[(k + 1) * 8 + c], acc);
    acc = fmaf(a.z, Wl[(k + 2) * 8 + c], acc);
    acc = fmaf(a.w, Wl[(k + 3) * 8 + c], acc);
  }
  out[(size_t)r * 8 + c] = acc;
}

// ---------------- graph mean stage 1: 64 graphs x GK chunk-blocks, no atomics ----------------
__global__ __launch_bounds__(256) void gpart_kernel(const float* __restrict__ HG, const int* __restrict__ gid,
                                                    float* __restrict__ partial, int n) {
  const int g = blockIdx.x >> 4;  // GK==16
  const int j = blockIdx.x & 15;
  int lo = 0, hi = n;
  while (lo < hi) { int mid = (lo + hi) >> 1; if (gid[mid] < g) lo = mid + 1; else hi = mid; }
  const int beg = lo;
  lo = 0; hi = n;
  while (lo < hi) { int mid = (lo + hi) >> 1; if (gid[mid] < g + 1) lo = mid + 1; else hi = mid; }
  const int end = lo;
  const int len = end - beg;
  const int chunk = (len + GK - 1) / GK;
  const int r0 = beg + j * chunk;
  const int r1 = min(r0 + chunk, end);

  const int c = threadIdx.x & 127;
  const int half = threadIdx.x >> 7;
  float s = 0.f;
  for (int r = r0 + half; r < r1; r += 2)
    s += HG[(size_t)r * HD + c];

  __shared__ float sh[256];
  sh[threadIdx.x] = s;
  __syncthreads();
  if (threadIdx.x < 128)
    partial[(size_t)blockIdx.x * HD + threadIdx.x] = sh[threadIdx.x] + sh[threadIdx.x + 128];
}

// ---------------- graph mean stage 2: reduce GK partials, scale, @Wgc + bgc ----------------
__global__ __launch_bounds__(128) void gfin_kernel(const float* __restrict__ partial, const int* __restrict__ gid,
                                                   const float* __restrict__ Wgc, const float* __restrict__ bgc,
                                                   float* __restrict__ out, int n) {
  const int g = blockIdx.x;
  int lo = 0, hi = n;
  while (lo < hi) { int mid = (lo + hi) >> 1; if (gid[mid] < g) lo = mid + 1; else hi = mid; }
  const int beg = lo;
  lo = 0; hi = n;
  while (lo < hi) { int mid = (lo + hi) >> 1; if (gid[mid] < g + 1) lo = mid + 1; else hi = mid; }
  const int end = lo;
  float cntf = (float)(end - beg);
  float inv = 1.f / (cntf > 1.f ? cntf : 1.f);

  const int c = threadIdx.x;  // 128
  float s = 0.f;
#pragma unroll
  for (int j = 0; j < GK; j++) s += partial[(size_t)(g * GK + j) * HD + c];
  __shared__ float sh[128];
  sh[c] = s * inv;
  __syncthreads();
  if (c < 4) {
    float acc = bgc[c];
    for (int k = 0; k < HD; k++) acc = fmaf(sh[k], Wgc[k * 4 + c], acc);
    out[g * 4 + c] = acc;
  }
}

extern "C" void kernel_launch(void* const* d_in, const int* in_sizes, int n_in,
                              void* d_out, int out_size, void* d_ws, size_t ws_size,
                              hipStream_t stream) {
  const float* node_feat = (const float*)d_in[0];
  const float* nodetype = (const float*)d_in[1];
  // d_in[2] edge_feat: dead branch, unused
  const float* W1 = (const float*)d_in[3];
  const float* b1 = (const float*)d_in[4];
  const float* g1 = (const float*)d_in[5];
  const float* be1 = (const float*)d_in[6];
  const float* W2 = (const float*)d_in[7];
  const float* b2 = (const float*)d_in[8];
  const float* g2 = (const float*)d_in[9];
  const float* be2 = (const float*)d_in[10];
  // 11 We, 12 b_e: dead
  const float* Wn1 = (const float*)d_in[13];
  const float* bn1 = (const float*)d_in[14];
  const float* Wn2 = (const float*)d_in[15];
  const float* bn2 = (const float*)d_in[16];
  const float* Wnc = (const float*)d_in[17];
  const float* bnc = (const float*)d_in[18];
  const float* Wg1 = (const float*)d_in[19];
  const float* bg1 = (const float*)d_in[20];
  const float* Wgc = (const float*)d_in[21];
  const float* bgc = (const float*)d_in[22];
  const int* src = (const int*)d_in[23];
  const int* dst = (const int*)d_in[24];
  const int* gid = (const int*)d_in[25];

  const int n = NN, e = NE;

  // ---- workspace carve (256B aligned), ~82 MB ----
  char* w = (char*)d_ws;
  auto alloc = [&](size_t bytes) -> void* {
    void* p = (void*)w;
    w += (bytes + 255) & ~(size_t)255;
    return p;
  };
  float* T1 = (float*)alloc((size_t)n * HD * 4);  // mm out; ALSO aliases deghist partials (dead before L1)
  float* AX = (float*)alloc((size_t)n * HD * 4);  // L1 agg out / L3 agg out / L4 agg out (disjoint ranges)
  float* A2 = (float*)alloc((size_t)n * HD * 4);  // L2 agg out (pre-BN), read by L3 & L5 mm
  int* hpart = (int*)T1;                          // 4*HNB*25000*4 B = 25.6 MB == sizeof(T1)
  int* csr_src = (int*)alloc((size_t)e * 4);
  int* row_ptr = (int*)alloc((size_t)(n + 1) * 4);
  int* cursor = (int*)alloc((size_t)n * 4);
  int* incnt = (int*)alloc((size_t)n * 4);
  int* excl = (int*)alloc((size_t)n * 4);
  int* bsum = (int*)alloc(256 * 4);
  float* rs_out = (float*)alloc((size_t)n * 4);
  float* rs_in = (float*)alloc((size_t)n * 4);
  float* sums = (float*)alloc(256 * 4);
  float* bnp1 = (float*)alloc(256 * 4);
  float* bnp2 = (float*)alloc(256 * 4);
  unsigned short* Wp = (unsigned short*)alloc(5 * 32768 * 2);
  float* partial = (float*)alloc((size_t)64 * GK * HD * 4);

  const int EB = (e + 255) / 256;
  const int NB = (n + 255) / 256;
  const int MMB = (n + 63) / 64;
  const int AGB = (n + 3) / 4;
  const int NOB = (n * 8 + 255) / 256;

  // ---- weight pack ----
  convw_kernel<<<5, 256, 0, stream>>>(W1, W2, Wn1, Wn2, Wg1, Wp);

  // ---- degrees (LDS-privatized, atomic-free) + CSR build ----
  deghist_kernel<<<HNB * 4, 256, 0, stream>>>(src, dst, hpart, e);
  degred_kernel<<<NB, 256, 0, stream>>>(hpart, incnt, rs_out, rs_in, n);
  scan1_kernel<<<NB, 256, 0, stream>>>(incnt, excl, bsum, n);
  scan2_kernel<<<1, 256, 0, stream>>>(bsum, NB);
  scan3_kernel<<<NB, 256, 0, stream>>>(excl, bsum, row_ptr, cursor, n, e);
  fill_kernel<<<EB, 256, 0, stream>>>(src, dst, cursor, csr_src, e);

  // ---- layer 1: h1 = bn-input = agg(node_feat @ W1) ----
  mmfma_kernel<0><<<MMB, 256, 0, stream>>>(node_feat, nullptr, Wp + 0 * 32768, rs_out, nullptr, nullptr, T1, n);
  agg_kernel<<<AGB, 256, 0, stream>>>(T1, row_ptr, csr_src, rs_in, b1, AX, n, 0);
  hipMemsetAsync(sums, 0, 256 * 4, stream);
  stats_kernel<<<256, 256, 0, stream>>>(AX, n, sums);
  bnfin_kernel<<<1, 128, 0, stream>>>(sums, g1, be1, bnp1, (float)n);

  // ---- layer 2: (BN1+lrelu fused into mm read) ----
  mmfma_kernel<1><<<MMB, 256, 0, stream>>>(AX, bnp1, Wp + 1 * 32768, rs_out, nullptr, nullptr, T1, n);
  agg_kernel<<<AGB, 256, 0, stream>>>(T1, row_ptr, csr_src, rs_in, b2, A2, n, 0);
  hipMemsetAsync(sums, 0, 256 * 4, stream);
  stats_kernel<<<256, 256, 0, stream>>>(A2, n, sums);
  bnfin_kernel<<<1, 128, 0, stream>>>(sums, g2, be2, bnp2, (float)n);

  // ---- layer 3: hn = lrelu(agg(h @ Wn1)) ; h = BN2(A2) fused into mm read ----
  mmfma_kernel<1><<<MMB, 256, 0, stream>>>(A2, bnp2, Wp + 2 * 32768, rs_out, nullptr, nullptr, T1, n);
  agg_kernel<<<AGB, 256, 0, stream>>>(T1, row_ptr, csr_src, rs_in, bn1, AX, n, 1);

  // ---- layer 4: hn = lrelu(agg(hn @ Wn2)) ----
  mmfma_kernel<0><<<MMB, 256, 0, stream>>>(AX, nullptr, Wp + 3 * 32768, rs_out, nullptr, nullptr, T1, n);
  agg_kernel<<<AGB, 256, 0, stream>>>(T1, row_ptr, csr_src, rs_in, bn2, AX, n, 1);

  // ---- node_out = hn @ Wnc + b_nc ----
  nodeout_kernel<<<NOB, 256, 0, stream>>>(AX, Wnc, bnc, (float*)d_out, n);

  // ---- layer 5: hg = lrelu(agg([h|nodetype] @ Wg1)) via rank-1 fold; h = BN2(A2) fused ----
  mmfma_kernel<1><<<MMB, 256, 0, stream>>>(A2, bnp2, Wp + 4 * 32768, rs_out, nodetype, Wg1 + HD * HD, T1, n);
  agg_kernel<<<AGB, 256, 0, stream>>>(T1, row_ptr, csr_src, rs_in, bg1, AX, n, 1);

  // ---- graph mean (two-stage, no atomics) + graph_out ----
  gpart_kernel<<<64 * GK, 256, 0, stream>>>(AX, gid, partial, n);
  gfin_kernel<<<64, 128, 0, stream>>>(partial, gid, Wgc, bgc, (float*)d_out + (size_t)n * 8, n);
}

// Round 6
// 469.294 us; speedup vs baseline: 3.4476x; 1.1881x over previous
//
#include <hip/hip_runtime.h>
#include <cstdint>
#include <cstddef>

#define NN 50000
#define NE 800000
#define HD 128
#define GK 16     // chunk-blocks per graph in gpart
#define HNB 64    // edge-slice blocks per (array,half) in deghist

typedef __attribute__((ext_vector_type(8))) short bf16x8;
typedef __attribute__((ext_vector_type(4))) float f32x4;
typedef _Float16 f16x2 __attribute__((ext_vector_type(2)));

__device__ inline unsigned short f2bf(float x) {
  unsigned u = __float_as_uint(x);
  u += 0x7FFF + ((u >> 16) & 1);  // round-to-nearest-even
  return (unsigned short)(u >> 16);
}
__device__ inline float bf2f(unsigned short h) { return __uint_as_float((unsigned)h << 16); }

// ---------------- degree histogram via LDS privatization (no global atomics) ----------------
__global__ __launch_bounds__(256) void deghist_kernel(const int* __restrict__ src, const int* __restrict__ dst,
                                                      int* __restrict__ part, int e) {
  __shared__ int hist[25000];  // 100 KB
  const int b = blockIdx.x >> 2;
  const int sel = (blockIdx.x >> 1) & 1;
  const int h = blockIdx.x & 1;
  const int* arr = sel ? dst : src;
  for (int i = threadIdx.x; i < 25000; i += 256) hist[i] = 0;
  __syncthreads();
  const int lo = h * 25000;
  const int slice = e >> 6;  // 12500
  const int base = b * slice;
  for (int i = base + threadIdx.x; i < base + slice; i += 256) {
    int v = arr[i] - lo;
    if ((unsigned)v < 25000u) atomicAdd(&hist[v], 1);  // LDS atomic: CU-local
  }
  __syncthreads();
  int* out = part + ((size_t)(sel * 2 + h) * HNB + b) * 25000;
  for (int i = threadIdx.x; i < 25000; i += 256) out[i] = hist[i];
}

__global__ __launch_bounds__(256) void degred_kernel(const int* __restrict__ part, int* __restrict__ incnt,
                                                     float* __restrict__ rs_out, float* __restrict__ rs_in, int n) {
  int v = blockIdx.x * 256 + threadIdx.x;
  if (v >= n) return;
  const int h = (v >= 25000) ? 1 : 0;
  const int bin = v - h * 25000;
  const int* p0 = part + ((size_t)(0 + h) * HNB) * 25000 + bin;  // src -> out-deg
  const int* p1 = part + ((size_t)(2 + h) * HNB) * 25000 + bin;  // dst -> in-deg
  int os = 0, is = 0;
#pragma unroll 8
  for (int b = 0; b < HNB; b++) {
    os += p0[(size_t)b * 25000];
    is += p1[(size_t)b * 25000];
  }
  incnt[v] = is;
  rs_out[v] = rsqrtf((float)(os > 1 ? os : 1));
  rs_in[v] = rsqrtf((float)(is > 1 ? is : 1));
}

// ---------------- exclusive scan (3-kernel) ----------------
__global__ __launch_bounds__(256) void scan1_kernel(const int* __restrict__ cnt, int* __restrict__ excl,
                                                    int* __restrict__ bsum, int n) {
  __shared__ int sh[256];
  int i = blockIdx.x * 256 + threadIdx.x;
  int v = (i < n) ? cnt[i] : 0;
  sh[threadIdx.x] = v;
  __syncthreads();
  for (int off = 1; off < 256; off <<= 1) {
    int x = (threadIdx.x >= off) ? sh[threadIdx.x - off] : 0;
    __syncthreads();
    sh[threadIdx.x] += x;
    __syncthreads();
  }
  if (i < n) excl[i] = sh[threadIdx.x] - v;
  if (threadIdx.x == 255) bsum[blockIdx.x] = sh[255];
}

__global__ __launch_bounds__(256) void scan2_kernel(int* __restrict__ bsum, int nb) {
  __shared__ int sh[256];
  int v = (threadIdx.x < nb) ? bsum[threadIdx.x] : 0;
  sh[threadIdx.x] = v;
  __syncthreads();
  for (int off = 1; off < 256; off <<= 1) {
    int x = (threadIdx.x >= off) ? sh[threadIdx.x - off] : 0;
    __syncthreads();
    sh[threadIdx.x] += x;
    __syncthreads();
  }
  if (threadIdx.x < nb) bsum[threadIdx.x] = sh[threadIdx.x] - v;
}

__global__ __launch_bounds__(256) void scan3_kernel(const int* __restrict__ excl, const int* __restrict__ bsum,
                                                    int* __restrict__ row_ptr, int* __restrict__ cursor,
                                                    int n, int e) {
  int i = blockIdx.x * 256 + threadIdx.x;
  if (i < n) {
    int v = excl[i] + bsum[blockIdx.x];
    row_ptr[i] = v;
    cursor[i] = v;
  }
  if (i == 0) row_ptr[n] = e;
}

__global__ __launch_bounds__(256) void fill_kernel(const int* __restrict__ src, const int* __restrict__ dst,
                                                   int* __restrict__ cursor, int* __restrict__ csr_src, int e) {
  int i = blockIdx.x * 256 + threadIdx.x;
  if (i < e) {
    int pos = atomicAdd(&cursor[dst[i]], 1);
    csr_src[pos] = src[i];
  }
}

// ---------------- weight pack: f32 [128][128] -> hi/lo bf16 in MFMA B-fragment order ----------------
__global__ __launch_bounds__(256) void convw_kernel(const float* __restrict__ W1, const float* __restrict__ W2,
                                                    const float* __restrict__ Wn1, const float* __restrict__ Wn2,
                                                    const float* __restrict__ Wg1, unsigned short* __restrict__ Wp) {
  const float* Ws[5] = {W1, W2, Wn1, Wn2, Wg1};
  const float* W = Ws[blockIdx.x];
  unsigned short* hi = Wp + (size_t)blockIdx.x * 32768;
  unsigned short* lo = hi + 16384;
  for (int s = threadIdx.x; s < 2048; s += 256) {
    int f = s >> 6, lane = s & 63;
    int ct = f >> 2, ks = f & 3;
    int col = ct * 16 + (lane & 15);
    int k0 = ks * 32 + ((lane >> 4) << 3);
    for (int j = 0; j < 8; j++) {
      float v = W[(k0 + j) * HD + col];
      unsigned short h = f2bf(v);
      hi[s * 8 + j] = h;
      lo[s * 8 + j] = f2bf(v - bf2f(h));
    }
  }
}

// ---------------- MFMA GEMM with fused input transform; fp16 output ----------------
// MODE 0: A is f32, split to hi/lo in-reg.  MODE 1: apply BN (x*bnp[c]+bnp[128+c]) + lrelu first.
// C[r][c] = fp16( (sum_k A'[r][k]*W[k][c] (+ evec[r]*erow[c])) * rs[r] )
template <int MODE>
__global__ __launch_bounds__(256) void mmfma_kernel(const float* __restrict__ A,
                                                    const float* __restrict__ bnp,
                                                    const unsigned short* __restrict__ Wp,
                                                    const float* __restrict__ rs,
                                                    const float* __restrict__ evec,
                                                    const float* __restrict__ erow,
                                                    _Float16* __restrict__ C, int n) {
  const int lane = threadIdx.x & 63;
  const int wv = threadIdx.x >> 6;
  const int rbase = (blockIdx.x * 4 + wv) * 16;
  if (rbase >= n) return;
  const int rA = min(rbase + (lane & 15), n - 1);
  const int koff = (lane >> 4) << 3;
  const unsigned short* wlo = Wp + 16384;
  f32x4 acc[8];
#pragma unroll
  for (int t = 0; t < 8; t++) acc[t] = (f32x4){0.f, 0.f, 0.f, 0.f};
#pragma unroll
  for (int ks = 0; ks < 4; ks++) {
    const int c0 = ks * 32 + koff;
    const float* ap = A + (size_t)rA * HD + c0;
    float4 a0 = *reinterpret_cast<const float4*>(ap);
    float4 a1 = *reinterpret_cast<const float4*>(ap + 4);
    float av[8] = {a0.x, a0.y, a0.z, a0.w, a1.x, a1.y, a1.z, a1.w};
    if (MODE == 1) {
      float4 s0 = *reinterpret_cast<const float4*>(bnp + c0);
      float4 s1 = *reinterpret_cast<const float4*>(bnp + c0 + 4);
      float4 t0 = *reinterpret_cast<const float4*>(bnp + 128 + c0);
      float4 t1 = *reinterpret_cast<const float4*>(bnp + 128 + c0 + 4);
      float sc[8] = {s0.x, s0.y, s0.z, s0.w, s1.x, s1.y, s1.z, s1.w};
      float sf[8] = {t0.x, t0.y, t0.z, t0.w, t1.x, t1.y, t1.z, t1.w};
#pragma unroll
      for (int j = 0; j < 8; j++) {
        float x = fmaf(av[j], sc[j], sf[j]);
        av[j] = x >= 0.f ? x : 0.01f * x;
      }
    }
    bf16x8 ah, al;
#pragma unroll
    for (int j = 0; j < 8; j++) {
      unsigned short hh = f2bf(av[j]);
      ((short*)&ah)[j] = (short)hh;
      ((short*)&al)[j] = (short)f2bf(av[j] - bf2f(hh));
    }
#pragma unroll
    for (int ct = 0; ct < 8; ct++) {
      int fo = ((ct * 4 + ks) * 64 + lane) * 8;
      bf16x8 bh = *reinterpret_cast<const bf16x8*>(Wp + fo);
      bf16x8 bl = *reinterpret_cast<const bf16x8*>(wlo + fo);
      acc[ct] = __builtin_amdgcn_mfma_f32_16x16x32_bf16(ah, bh, acc[ct], 0, 0, 0);
      acc[ct] = __builtin_amdgcn_mfma_f32_16x16x32_bf16(al, bh, acc[ct], 0, 0, 0);
      acc[ct] = __builtin_amdgcn_mfma_f32_16x16x32_bf16(ah, bl, acc[ct], 0, 0, 0);
    }
  }
  const int r0 = rbase + ((lane >> 4) << 2);
  const int cbase = lane & 15;
#pragma unroll
  for (int i = 0; i < 4; i++) {
    int r = r0 + i;
    if (r < n) {
      float rsv = rs[r];
      float ev = (evec != nullptr) ? evec[r] : 0.f;
      _Float16* crow = C + (size_t)r * HD + cbase;
#pragma unroll
      for (int ct = 0; ct < 8; ct++) {
        float v = acc[ct][i];
        if (evec != nullptr) v = fmaf(ev, erow[ct * 16 + cbase], v);
        crow[ct * 16] = (_Float16)(v * rsv);
      }
    }
  }
}

// ---------------- pull-mode normalized aggregation (one wave per dst node, 8-edge ILP, fp16 gather) ----------------
__global__ __launch_bounds__(256) void agg_kernel(const _Float16* __restrict__ Ys, const int* __restrict__ row_ptr,
                                                  const int* __restrict__ csr_src, const float* __restrict__ rs_in,
                                                  const float* __restrict__ bias, float* __restrict__ out,
                                                  int n, int do_lrelu) {
  int wave = threadIdx.x >> 6;
  int lane = threadIdx.x & 63;
  int node = blockIdx.x * 4 + wave;
  if (node >= n) return;
  int beg = row_ptr[node], end = row_ptr[node + 1];
  float ax = 0.f, ay = 0.f;
  int e = beg;
  for (; e + 7 < end; e += 8) {
    int s[8];
#pragma unroll
    for (int j = 0; j < 8; j++) s[j] = csr_src[e + j];  // wave-uniform -> scalar loads
    f16x2 v[8];
#pragma unroll
    for (int j = 0; j < 8; j++) v[j] = reinterpret_cast<const f16x2*>(Ys + (size_t)s[j] * HD)[lane];
#pragma unroll
    for (int j = 0; j < 8; j++) {
      ax += (float)v[j].x;
      ay += (float)v[j].y;
    }
  }
  for (; e < end; ++e) {
    int s = csr_src[e];
    f16x2 v = reinterpret_cast<const f16x2*>(Ys + (size_t)s * HD)[lane];
    ax += (float)v.x;
    ay += (float)v.y;
  }
  float ri = rs_in[node];
  float2 b = reinterpret_cast<const float2*>(bias)[lane];
  float ox = fmaf(ax, ri, b.x);
  float oy = fmaf(ay, ri, b.y);
  if (do_lrelu) {
    ox = ox >= 0.f ? ox : 0.01f * ox;
    oy = oy >= 0.f ? oy : 0.01f * oy;
  }
  reinterpret_cast<float2*>(out + (size_t)node * HD)[lane] = make_float2(ox, oy);
}

// ---------------- BN statistics (column sums / sumsq) ----------------
__global__ __launch_bounds__(256) void stats_kernel(const float* __restrict__ Z, int n, float* __restrict__ sums) {
  int c = threadIdx.x & 127;
  int half = threadIdx.x >> 7;
  float s = 0.f, s2 = 0.f;
  for (int r = blockIdx.x * 2 + half; r < n; r += gridDim.x * 2) {
    float v = Z[(size_t)r * HD + c];
    s += v;
    s2 = fmaf(v, v, s2);
  }
  __shared__ float ls[512];
  ls[threadIdx.x] = s;
  ls[256 + threadIdx.x] = s2;
  __syncthreads();
  if (threadIdx.x < 128) {
    atomicAdd(&sums[c], ls[threadIdx.x] + ls[threadIdx.x + 128]);
    atomicAdd(&sums[128 + c], ls[256 + threadIdx.x] + ls[256 + threadIdx.x + 128]);
  }
}

__global__ void bnfin_kernel(const float* __restrict__ sums, const float* __restrict__ gamma,
                             const float* __restrict__ beta, float* __restrict__ bnp, float n) {
  int c = threadIdx.x;  // 128
  float mu = sums[c] / n;
  float var = sums[128 + c] / n - mu * mu;
  if (var < 0.f) var = 0.f;
  float sc = gamma[c] * rsqrtf(var + 1e-5f);
  bnp[c] = sc;
  bnp[128 + c] = fmaf(-mu, sc, beta[c]);
}

// ---------------- node_out = X@Wnc + b_nc  ([n,128]@[128,8]) ----------------
__global__ __launch_bounds__(256) void nodeout_kernel(const float* __restrict__ X, const float* __restrict__ Wnc,
                                                      const float* __restrict__ b, float* __restrict__ out, int n) {
  __shared__ float Wl[HD * 8];
  __shared__ float bl[8];
  for (int i = threadIdx.x; i < HD * 8; i += 256) Wl[i] = Wnc[i];
  if (threadIdx.x < 8) bl[threadIdx.x] = b[threadIdx.x];
  __syncthreads();
  int t = blockIdx.x * 256 + threadIdx.x;
  int r = t >> 3, c = t & 7;
  if (r >= n) return;
  const float* x = X + (size_t)r * HD;
  float acc = bl[c];
  for (int k = 0; k < HD; k += 4) {
    float4 a = *reinterpret_cast<const float4*>(x + k);
    acc = fmaf(a.x, Wl[k * 8 + c], acc);
    acc = fmaf(a.y, Wl[(k + 1) * 8 + c], acc);
    acc = fmaf(a.z, Wl[(k + 2) * 8 + c], acc);
    acc = fmaf(a.w, Wl[(k + 3) * 8 + c], acc);
  }
  out[(size_t)r * 8 + c] = acc;
}

// ---------------- graph mean stage 1: 64 graphs x GK chunk-blocks, no atomics ----------------
__global__ __launch_bounds__(256) void gpart_kernel(const float* __restrict__ HG, const int* __restrict__ gid,
                                                    float* __restrict__ partial, int n) {
  const int g = blockIdx.x >> 4;  // GK==16
  const int j = blockIdx.x & 15;
  int lo = 0, hi = n;
  while (lo < hi) { int mid = (lo + hi) >> 1; if (gid[mid] < g) lo = mid + 1; else hi = mid; }
  const int beg = lo;
  lo = 0; hi = n;
  while (lo < hi) { int mid = (lo + hi) >> 1; if (gid[mid] < g + 1) lo = mid + 1; else hi = mid; }
  const int end = lo;
  const int len = end - beg;
  const int chunk = (len + GK - 1) / GK;
  const int r0 = beg + j * chunk;
  const int r1 = min(r0 + chunk, end);

  const int c = threadIdx.x & 127;
  const int half = threadIdx.x >> 7;
  float s = 0.f;
  for (int r = r0 + half; r < r1; r += 2)
    s += HG[(size_t)r * HD + c];

  __shared__ float sh[256];
  sh[threadIdx.x] = s;
  __syncthreads();
  if (threadIdx.x < 128)
    partial[(size_t)blockIdx.x * HD + threadIdx.x] = sh[threadIdx.x] + sh[threadIdx.x + 128];
}

// ---------------- graph mean stage 2: reduce GK partials, scale, @Wgc + bgc ----------------
__global__ __launch_bounds__(128) void gfin_kernel(const float* __restrict__ partial, const int* __restrict__ gid,
                                                   const float* __restrict__ Wgc, const float* __restrict__ bgc,
                                                   float* __restrict__ out, int n) {
  const int g = blockIdx.x;
  int lo = 0, hi = n;
  while (lo < hi) { int mid = (lo + hi) >> 1; if (gid[mid] < g) lo = mid + 1; else hi = mid; }
  const int beg = lo;
  lo = 0; hi = n;
  while (lo < hi) { int mid = (lo + hi) >> 1; if (gid[mid] < g + 1) lo = mid + 1; else hi = mid; }
  const int end = lo;
  float cntf = (float)(end - beg);
  float inv = 1.f / (cntf > 1.f ? cntf : 1.f);

  const int c = threadIdx.x;  // 128
  float s = 0.f;
#pragma unroll
  for (int j = 0; j < GK; j++) s += partial[(size_t)(g * GK + j) * HD + c];
  __shared__ float sh[128];
  sh[c] = s * inv;
  __syncthreads();
  if (c < 4) {
    float acc = bgc[c];
    for (int k = 0; k < HD; k++) acc = fmaf(sh[k], Wgc[k * 4 + c], acc);
    out[g * 4 + c] = acc;
  }
}

extern "C" void kernel_launch(void* const* d_in, const int* in_sizes, int n_in,
                              void* d_out, int out_size, void* d_ws, size_t ws_size,
                              hipStream_t stream) {
  const float* node_feat = (const float*)d_in[0];
  const float* nodetype = (const float*)d_in[1];
  // d_in[2] edge_feat: dead branch, unused
  const float* W1 = (const float*)d_in[3];
  const float* b1 = (const float*)d_in[4];
  const float* g1 = (const float*)d_in[5];
  const float* be1 = (const float*)d_in[6];
  const float* W2 = (const float*)d_in[7];
  const float* b2 = (const float*)d_in[8];
  const float* g2 = (const float*)d_in[9];
  const float* be2 = (const float*)d_in[10];
  // 11 We, 12 b_e: dead
  const float* Wn1 = (const float*)d_in[13];
  const float* bn1 = (const float*)d_in[14];
  const float* Wn2 = (const float*)d_in[15];
  const float* bn2 = (const float*)d_in[16];
  const float* Wnc = (const float*)d_in[17];
  const float* bnc = (const float*)d_in[18];
  const float* Wg1 = (const float*)d_in[19];
  const float* bg1 = (const float*)d_in[20];
  const float* Wgc = (const float*)d_in[21];
  const float* bgc = (const float*)d_in[22];
  const int* src = (const int*)d_in[23];
  const int* dst = (const int*)d_in[24];
  const int* gid = (const int*)d_in[25];

  const int n = NN, e = NE;

  // ---- workspace carve (256B aligned) ----
  char* w = (char*)d_ws;
  auto alloc = [&](size_t bytes) -> void* {
    void* p = (void*)w;
    w += (bytes + 255) & ~(size_t)255;
    return p;
  };
  _Float16* T1 = (_Float16*)alloc((size_t)n * HD * 4);  // fp16 mm out (uses half of this); aliases deghist partials
  float* AX = (float*)alloc((size_t)n * HD * 4);        // L1/L3/L4/L5 agg out (disjoint live ranges)
  float* A2 = (float*)alloc((size_t)n * HD * 4);        // L2 agg out (pre-BN), read by L3 & L5 mm
  int* hpart = (int*)T1;                                // 4*HNB*25000*4 B = 25.6 MB == sizeof(T1 region)
  int* csr_src = (int*)alloc((size_t)e * 4);
  int* row_ptr = (int*)alloc((size_t)(n + 1) * 4);
  int* cursor = (int*)alloc((size_t)n * 4);
  int* incnt = (int*)alloc((size_t)n * 4);
  int* excl = (int*)alloc((size_t)n * 4);
  int* bsum = (int*)alloc(256 * 4);
  float* rs_out = (float*)alloc((size_t)n * 4);
  float* rs_in = (float*)alloc((size_t)n * 4);
  float* sums = (float*)alloc(256 * 4);
  float* bnp1 = (float*)alloc(256 * 4);
  float* bnp2 = (float*)alloc(256 * 4);
  unsigned short* Wp = (unsigned short*)alloc(5 * 32768 * 2);
  float* partial = (float*)alloc((size_t)64 * GK * HD * 4);

  const int EB = (e + 255) / 256;
  const int NB = (n + 255) / 256;
  const int MMB = (n + 63) / 64;
  const int AGB = (n + 3) / 4;
  const int NOB = (n * 8 + 255) / 256;

  // ---- weight pack ----
  convw_kernel<<<5, 256, 0, stream>>>(W1, W2, Wn1, Wn2, Wg1, Wp);

  // ---- degrees (LDS-privatized, atomic-free) + CSR build ----
  deghist_kernel<<<HNB * 4, 256, 0, stream>>>(src, dst, hpart, e);
  degred_kernel<<<NB, 256, 0, stream>>>(hpart, incnt, rs_out, rs_in, n);
  scan1_kernel<<<NB, 256, 0, stream>>>(incnt, excl, bsum, n);
  scan2_kernel<<<1, 256, 0, stream>>>(bsum, NB);
  scan3_kernel<<<NB, 256, 0, stream>>>(excl, bsum, row_ptr, cursor, n, e);
  fill_kernel<<<EB, 256, 0, stream>>>(src, dst, cursor, csr_src, e);

  // ---- layer 1 ----
  mmfma_kernel<0><<<MMB, 256, 0, stream>>>(node_feat, nullptr, Wp + 0 * 32768, rs_out, nullptr, nullptr, T1, n);
  agg_kernel<<<AGB, 256, 0, stream>>>(T1, row_ptr, csr_src, rs_in, b1, AX, n, 0);
  hipMemsetAsync(sums, 0, 256 * 4, stream);
  stats_kernel<<<256, 256, 0, stream>>>(AX, n, sums);
  bnfin_kernel<<<1, 128, 0, stream>>>(sums, g1, be1, bnp1, (float)n);

  // ---- layer 2 (BN1+lrelu fused into mm read) ----
  mmfma_kernel<1><<<MMB, 256, 0, stream>>>(AX, bnp1, Wp + 1 * 32768, rs_out, nullptr, nullptr, T1, n);
  agg_kernel<<<AGB, 256, 0, stream>>>(T1, row_ptr, csr_src, rs_in, b2, A2, n, 0);
  hipMemsetAsync(sums, 0, 256 * 4, stream);
  stats_kernel<<<256, 256, 0, stream>>>(A2, n, sums);
  bnfin_kernel<<<1, 128, 0, stream>>>(sums, g2, be2, bnp2, (float)n);

  // ---- layer 3 (BN2 fused into mm read) ----
  mmfma_kernel<1><<<MMB, 256, 0, stream>>>(A2, bnp2, Wp + 2 * 32768, rs_out, nullptr, nullptr, T1, n);
  agg_kernel<<<AGB, 256, 0, stream>>>(T1, row_ptr, csr_src, rs_in, bn1, AX, n, 1);

  // ---- layer 4 ----
  mmfma_kernel<0><<<MMB, 256, 0, stream>>>(AX, nullptr, Wp + 3 * 32768, rs_out, nullptr, nullptr, T1, n);
  agg_kernel<<<AGB, 256, 0, stream>>>(T1, row_ptr, csr_src, rs_in, bn2, AX, n, 1);

  // ---- node_out ----
  nodeout_kernel<<<NOB, 256, 0, stream>>>(AX, Wnc, bnc, (float*)d_out, n);

  // ---- layer 5 (rank-1 fold; BN2 fused) ----
  mmfma_kernel<1><<<MMB, 256, 0, stream>>>(A2, bnp2, Wp + 4 * 32768, rs_out, nodetype, Wg1 + HD * HD, T1, n);
  agg_kernel<<<AGB, 256, 0, stream>>>(T1, row_ptr, csr_src, rs_in, bg1, AX, n, 1);

  // ---- graph mean (two-stage, no atomics) + graph_out ----
  gpart_kernel<<<64 * GK, 256, 0, stream>>>(AX, gid, partial, n);
  gfin_kernel<<<64, 128, 0, stream>>>(partial, gid, Wgc, bgc, (float*)d_out + (size_t)n * 8, n);
}

// Round 7
// 465.931 us; speedup vs baseline: 3.4725x; 1.0072x over previous
//
#include <hip/hip_runtime.h>
#include <cstdint>
#include <cstddef>

#define NN 50000
#define NE 800000
#define HD 128
#define GK 16     // chunk-blocks per graph in gpart
#define HNB 64    // edge-slice blocks per (array,half) in deghist

typedef __attribute__((ext_vector_type(8))) short bf16x8;
typedef __attribute__((ext_vector_type(4))) float f32x4;
typedef _Float16 f16x2 __attribute__((ext_vector_type(2)));

__device__ inline unsigned short f2bf(float x) {
  unsigned u = __float_as_uint(x);
  u += 0x7FFF + ((u >> 16) & 1);  // round-to-nearest-even
  return (unsigned short)(u >> 16);
}
__device__ inline float bf2f(unsigned short h) { return __uint_as_float((unsigned)h << 16); }

// ---------------- degree histogram via LDS privatization (no global atomics) ----------------
__global__ __launch_bounds__(256) void deghist_kernel(const int* __restrict__ src, const int* __restrict__ dst,
                                                      int* __restrict__ part, int e) {
  __shared__ int hist[25000];  // 100 KB
  const int b = blockIdx.x >> 2;
  const int sel = (blockIdx.x >> 1) & 1;
  const int h = blockIdx.x & 1;
  const int* arr = sel ? dst : src;
  for (int i = threadIdx.x; i < 25000; i += 256) hist[i] = 0;
  __syncthreads();
  const int lo = h * 25000;
  const int slice = e >> 6;  // 12500
  const int base = b * slice;
  for (int i = base + threadIdx.x; i < base + slice; i += 256) {
    int v = arr[i] - lo;
    if ((unsigned)v < 25000u) atomicAdd(&hist[v], 1);  // LDS atomic: CU-local
  }
  __syncthreads();
  int* out = part + ((size_t)(sel * 2 + h) * HNB + b) * 25000;
  for (int i = threadIdx.x; i < 25000; i += 256) out[i] = hist[i];
}

__global__ __launch_bounds__(256) void degred_kernel(const int* __restrict__ part, int* __restrict__ incnt,
                                                     float* __restrict__ rs_out, float* __restrict__ rs_in, int n) {
  int v = blockIdx.x * 256 + threadIdx.x;
  if (v >= n) return;
  const int h = (v >= 25000) ? 1 : 0;
  const int bin = v - h * 25000;
  const int* p0 = part + ((size_t)(0 + h) * HNB) * 25000 + bin;  // src -> out-deg
  const int* p1 = part + ((size_t)(2 + h) * HNB) * 25000 + bin;  // dst -> in-deg
  int os = 0, is = 0;
#pragma unroll 8
  for (int b = 0; b < HNB; b++) {
    os += p0[(size_t)b * 25000];
    is += p1[(size_t)b * 25000];
  }
  incnt[v] = is;
  rs_out[v] = rsqrtf((float)(os > 1 ? os : 1));
  rs_in[v] = rsqrtf((float)(is > 1 ? is : 1));
}

// ---------------- exclusive scan (3-kernel) ----------------
__global__ __launch_bounds__(256) void scan1_kernel(const int* __restrict__ cnt, int* __restrict__ excl,
                                                    int* __restrict__ bsum, int n) {
  __shared__ int sh[256];
  int i = blockIdx.x * 256 + threadIdx.x;
  int v = (i < n) ? cnt[i] : 0;
  sh[threadIdx.x] = v;
  __syncthreads();
  for (int off = 1; off < 256; off <<= 1) {
    int x = (threadIdx.x >= off) ? sh[threadIdx.x - off] : 0;
    __syncthreads();
    sh[threadIdx.x] += x;
    __syncthreads();
  }
  if (i < n) excl[i] = sh[threadIdx.x] - v;
  if (threadIdx.x == 255) bsum[blockIdx.x] = sh[255];
}

__global__ __launch_bounds__(256) void scan2_kernel(int* __restrict__ bsum, int nb) {
  __shared__ int sh[256];
  int v = (threadIdx.x < nb) ? bsum[threadIdx.x] : 0;
  sh[threadIdx.x] = v;
  __syncthreads();
  for (int off = 1; off < 256; off <<= 1) {
    int x = (threadIdx.x >= off) ? sh[threadIdx.x - off] : 0;
    __syncthreads();
    sh[threadIdx.x] += x;
    __syncthreads();
  }
  if (threadIdx.x < nb) bsum[threadIdx.x] = sh[threadIdx.x] - v;
}

__global__ __launch_bounds__(256) void scan3_kernel(const int* __restrict__ excl, const int* __restrict__ bsum,
                                                    int* __restrict__ row_ptr, int n, int e) {
  int i = blockIdx.x * 256 + threadIdx.x;
  if (i < n) row_ptr[i] = excl[i] + bsum[blockIdx.x];
  if (i == 0) row_ptr[n] = e;
}

// ---------------- per-(slice,half) start offsets: offs[b][h][bin] = row_ptr[v] + sum_{b'<b} hist_dst[b'][v] ----------------
__global__ __launch_bounds__(256) void scanoffs_kernel(const int* __restrict__ part, const int* __restrict__ row_ptr,
                                                       int* __restrict__ offs, int n) {
  int v = blockIdx.x * 256 + threadIdx.x;
  if (v >= n) return;
  const int h = (v >= 25000) ? 1 : 0;
  const int bin = v - h * 25000;
  const int* p = part + ((size_t)(2 + h) * HNB) * 25000 + bin;  // dst partials
  int run = row_ptr[v];
#pragma unroll 8
  for (int b = 0; b < HNB; b++) {
    offs[((size_t)(b * 2 + h)) * 25000 + bin] = run;
    run += p[(size_t)b * 25000];
  }
}

// ---------------- CSR fill with LDS cursors (no global atomics) ----------------
__global__ __launch_bounds__(256) void fill2_kernel(const int* __restrict__ src, const int* __restrict__ dst,
                                                    const int* __restrict__ offs, int* __restrict__ csr_src, int e) {
  __shared__ int cur[25000];  // 100 KB
  const int b = blockIdx.x >> 1;
  const int h = blockIdx.x & 1;
  const int* o = offs + ((size_t)(b * 2 + h)) * 25000;
  for (int i = threadIdx.x; i < 25000; i += 256) cur[i] = o[i];
  __syncthreads();
  const int lo = h * 25000;
  const int slice = e >> 6;  // 12500
  const int base = b * slice;
  for (int i = base + threadIdx.x; i < base + slice; i += 256) {
    int v = dst[i] - lo;
    if ((unsigned)v < 25000u) {
      int pos = atomicAdd(&cur[v], 1);  // LDS atomic: CU-local
      csr_src[pos] = src[i];
    }
  }
}

// ---------------- weight pack: f32 [128][128] -> hi/lo bf16 in MFMA B-fragment order ----------------
__global__ __launch_bounds__(256) void convw_kernel(const float* __restrict__ W1, const float* __restrict__ W2,
                                                    const float* __restrict__ Wn1, const float* __restrict__ Wn2,
                                                    const float* __restrict__ Wg1, unsigned short* __restrict__ Wp) {
  const float* Ws[5] = {W1, W2, Wn1, Wn2, Wg1};
  const float* W = Ws[blockIdx.x];
  unsigned short* hi = Wp + (size_t)blockIdx.x * 32768;
  unsigned short* lo = hi + 16384;
  for (int s = threadIdx.x; s < 2048; s += 256) {
    int f = s >> 6, lane = s & 63;
    int ct = f >> 2, ks = f & 3;
    int col = ct * 16 + (lane & 15);
    int k0 = ks * 32 + ((lane >> 4) << 3);
    for (int j = 0; j < 8; j++) {
      float v = W[(k0 + j) * HD + col];
      unsigned short h = f2bf(v);
      hi[s * 8 + j] = h;
      lo[s * 8 + j] = f2bf(v - bf2f(h));
    }
  }
}

// ---------------- MFMA GEMM with fused input transform; fp16 output ----------------
// MODE 0: A is f32, split to hi/lo in-reg.  MODE 1: apply BN (x*bnp[c]+bnp[128+c]) + lrelu first.
// C[r][c] = fp16( (sum_k A'[r][k]*W[k][c] (+ evec[r]*erow[c])) * rs[r] )
template <int MODE>
__global__ __launch_bounds__(256) void mmfma_kernel(const float* __restrict__ A,
                                                    const float* __restrict__ bnp,
                                                    const unsigned short* __restrict__ Wp,
                                                    const float* __restrict__ rs,
                                                    const float* __restrict__ evec,
                                                    const float* __restrict__ erow,
                                                    _Float16* __restrict__ C, int n) {
  const int lane = threadIdx.x & 63;
  const int wv = threadIdx.x >> 6;
  const int rbase = (blockIdx.x * 4 + wv) * 16;
  if (rbase >= n) return;
  const int rA = min(rbase + (lane & 15), n - 1);
  const int koff = (lane >> 4) << 3;
  const unsigned short* wlo = Wp + 16384;
  f32x4 acc[8];
#pragma unroll
  for (int t = 0; t < 8; t++) acc[t] = (f32x4){0.f, 0.f, 0.f, 0.f};
#pragma unroll
  for (int ks = 0; ks < 4; ks++) {
    const int c0 = ks * 32 + koff;
    const float* ap = A + (size_t)rA * HD + c0;
    float4 a0 = *reinterpret_cast<const float4*>(ap);
    float4 a1 = *reinterpret_cast<const float4*>(ap + 4);
    float av[8] = {a0.x, a0.y, a0.z, a0.w, a1.x, a1.y, a1.z, a1.w};
    if (MODE == 1) {
      float4 s0 = *reinterpret_cast<const float4*>(bnp + c0);
      float4 s1 = *reinterpret_cast<const float4*>(bnp + c0 + 4);
      float4 t0 = *reinterpret_cast<const float4*>(bnp + 128 + c0);
      float4 t1 = *reinterpret_cast<const float4*>(bnp + 128 + c0 + 4);
      float sc[8] = {s0.x, s0.y, s0.z, s0.w, s1.x, s1.y, s1.z, s1.w};
      float sf[8] = {t0.x, t0.y, t0.z, t0.w, t1.x, t1.y, t1.z, t1.w};
#pragma unroll
      for (int j = 0; j < 8; j++) {
        float x = fmaf(av[j], sc[j], sf[j]);
        av[j] = x >= 0.f ? x : 0.01f * x;
      }
    }
    bf16x8 ah, al;
#pragma unroll
    for (int j = 0; j < 8; j++) {
      unsigned short hh = f2bf(av[j]);
      ((short*)&ah)[j] = (short)hh;
      ((short*)&al)[j] = (short)f2bf(av[j] - bf2f(hh));
    }
#pragma unroll
    for (int ct = 0; ct < 8; ct++) {
      int fo = ((ct * 4 + ks) * 64 + lane) * 8;
      bf16x8 bh = *reinterpret_cast<const bf16x8*>(Wp + fo);
      bf16x8 bl = *reinterpret_cast<const bf16x8*>(wlo + fo);
      acc[ct] = __builtin_amdgcn_mfma_f32_16x16x32_bf16(ah, bh, acc[ct], 0, 0, 0);
      acc[ct] = __builtin_amdgcn_mfma_f32_16x16x32_bf16(al, bh, acc[ct], 0, 0, 0);
      acc[ct] = __builtin_amdgcn_mfma_f32_16x16x32_bf16(ah, bl, acc[ct], 0, 0, 0);
    }
  }
  const int r0 = rbase + ((lane >> 4) << 2);
  const int cbase = lane & 15;
#pragma unroll
  for (int i = 0; i < 4; i++) {
    int r = r0 + i;
    if (r < n) {
      float rsv = rs[r];
      float ev = (evec != nullptr) ? evec[r] : 0.f;
      _Float16* crow = C + (size_t)r * HD + cbase;
#pragma unroll
      for (int ct = 0; ct < 8; ct++) {
        float v = acc[ct][i];
        if (evec != nullptr) v = fmaf(ev, erow[ct * 16 + cbase], v);
        crow[ct * 16] = (_Float16)(v * rsv);
      }
    }
  }
}

// ---------------- pull-mode normalized aggregation (one wave per dst node, 8-edge ILP, fp16 gather) ----------------
__global__ __launch_bounds__(256) void agg_kernel(const _Float16* __restrict__ Ys, const int* __restrict__ row_ptr,
                                                  const int* __restrict__ csr_src, const float* __restrict__ rs_in,
                                                  const float* __restrict__ bias, float* __restrict__ out,
                                                  int n, int do_lrelu) {
  int wave = threadIdx.x >> 6;
  int lane = threadIdx.x & 63;
  int node = blockIdx.x * 4 + wave;
  if (node >= n) return;
  int beg = row_ptr[node], end = row_ptr[node + 1];
  float ax = 0.f, ay = 0.f;
  int e = beg;
  for (; e + 7 < end; e += 8) {
    int s[8];
#pragma unroll
    for (int j = 0; j < 8; j++) s[j] = csr_src[e + j];  // wave-uniform -> scalar loads
    f16x2 v[8];
#pragma unroll
    for (int j = 0; j < 8; j++) v[j] = reinterpret_cast<const f16x2*>(Ys + (size_t)s[j] * HD)[lane];
#pragma unroll
    for (int j = 0; j < 8; j++) {
      ax += (float)v[j].x;
      ay += (float)v[j].y;
    }
  }
  for (; e < end; ++e) {
    int s = csr_src[e];
    f16x2 v = reinterpret_cast<const f16x2*>(Ys + (size_t)s * HD)[lane];
    ax += (float)v.x;
    ay += (float)v.y;
  }
  float ri = rs_in[node];
  float2 b = reinterpret_cast<const float2*>(bias)[lane];
  float ox = fmaf(ax, ri, b.x);
  float oy = fmaf(ay, ri, b.y);
  if (do_lrelu) {
    ox = ox >= 0.f ? ox : 0.01f * ox;
    oy = oy >= 0.f ? oy : 0.01f * oy;
  }
  reinterpret_cast<float2*>(out + (size_t)node * HD)[lane] = make_float2(ox, oy);
}

// ---------------- BN statistics (column sums / sumsq) ----------------
__global__ __launch_bounds__(256) void stats_kernel(const float* __restrict__ Z, int n, float* __restrict__ sums) {
  int c = threadIdx.x & 127;
  int half = threadIdx.x >> 7;
  float s = 0.f, s2 = 0.f;
  for (int r = blockIdx.x * 2 + half; r < n; r += gridDim.x * 2) {
    float v = Z[(size_t)r * HD + c];
    s += v;
    s2 = fmaf(v, v, s2);
  }
  __shared__ float ls[512];
  ls[threadIdx.x] = s;
  ls[256 + threadIdx.x] = s2;
  __syncthreads();
  if (threadIdx.x < 128) {
    atomicAdd(&sums[c], ls[threadIdx.x] + ls[threadIdx.x + 128]);
    atomicAdd(&sums[128 + c], ls[256 + threadIdx.x] + ls[256 + threadIdx.x + 128]);
  }
}

__global__ void bnfin_kernel(const float* __restrict__ sums, const float* __restrict__ gamma,
                             const float* __restrict__ beta, float* __restrict__ bnp, float n) {
  int c = threadIdx.x;  // 128
  float mu = sums[c] / n;
  float var = sums[128 + c] / n - mu * mu;
  if (var < 0.f) var = 0.f;
  float sc = gamma[c] * rsqrtf(var + 1e-5f);
  bnp[c] = sc;
  bnp[128 + c] = fmaf(-mu, sc, beta[c]);
}

// ---------------- node_out = X@Wnc + b_nc  ([n,128]@[128,8]) ----------------
__global__ __launch_bounds__(256) void nodeout_kernel(const float* __restrict__ X, const float* __restrict__ Wnc,
                                                      const float* __restrict__ b, float* __restrict__ out, int n) {
  __shared__ float Wl[HD * 8];
  __shared__ float bl[8];
  for (int i = threadIdx.x; i < HD * 8; i += 256) Wl[i] = Wnc[i];
  if (threadIdx.x < 8) bl[threadIdx.x] = b[threadIdx.x];
  __syncthreads();
  int t = blockIdx.x * 256 + threadIdx.x;
  int r = t >> 3, c = t & 7;
  if (r >= n) return;
  const float* x = X + (size_t)r * HD;
  float acc = bl[c];
  for (int k = 0; k < HD; k += 4) {
    float4 a = *reinterpret_cast<const float4*>(x + k);
    acc = fmaf(a.x, Wl[k * 8 + c], acc);
    acc = fmaf(a.y, Wl[(k + 1) * 8 + c], acc);
    acc = fmaf(a.z, Wl[(k + 2) * 8 + c], acc);
    acc = fmaf(a.w, Wl[(k + 3) * 8 + c], acc);
  }
  out[(size_t)r * 8 + c] = acc;
}

// ---------------- graph mean stage 1: 64 graphs x GK chunk-blocks, no atomics ----------------
__global__ __launch_bounds__(256) void gpart_kernel(const float* __restrict__ HG, const int* __restrict__ gid,
                                                    float* __restrict__ partial, int n) {
  const int g = blockIdx.x >> 4;  // GK==16
  const int j = blockIdx.x & 15;
  int lo = 0, hi = n;
  while (lo < hi) { int mid = (lo + hi) >> 1; if (gid[mid] < g) lo = mid + 1; else hi = mid; }
  const int beg = lo;
  lo = 0; hi = n;
  while (lo < hi) { int mid = (lo + hi) >> 1; if (gid[mid] < g + 1) lo = mid + 1; else hi = mid; }
  const int end = lo;
  const int len = end - beg;
  const int chunk = (len + GK - 1) / GK;
  const int r0 = beg + j * chunk;
  const int r1 = min(r0 + chunk, end);

  const int c = threadIdx.x & 127;
  const int half = threadIdx.x >> 7;
  float s = 0.f;
  for (int r = r0 + half; r < r1; r += 2)
    s += HG[(size_t)r * HD + c];

  __shared__ float sh[256];
  sh[threadIdx.x] = s;
  __syncthreads();
  if (threadIdx.x < 128)
    partial[(size_t)blockIdx.x * HD + threadIdx.x] = sh[threadIdx.x] + sh[threadIdx.x + 128];
}

// ---------------- graph mean stage 2: reduce GK partials, scale, @Wgc + bgc ----------------
__global__ __launch_bounds__(128) void gfin_kernel(const float* __restrict__ partial, const int* __restrict__ gid,
                                                   const float* __restrict__ Wgc, const float* __restrict__ bgc,
                                                   float* __restrict__ out, int n) {
  const int g = blockIdx.x;
  int lo = 0, hi = n;
  while (lo < hi) { int mid = (lo + hi) >> 1; if (gid[mid] < g) lo = mid + 1; else hi = mid; }
  const int beg = lo;
  lo = 0; hi = n;
  while (lo < hi) { int mid = (lo + hi) >> 1; if (gid[mid] < g + 1) lo = mid + 1; else hi = mid; }
  const int end = lo;
  float cntf = (float)(end - beg);
  float inv = 1.f / (cntf > 1.f ? cntf : 1.f);

  const int c = threadIdx.x;  // 128
  float s = 0.f;
#pragma unroll
  for (int j = 0; j < GK; j++) s += partial[(size_t)(g * GK + j) * HD + c];
  __shared__ float sh[128];
  sh[c] = s * inv;
  __syncthreads();
  if (c < 4) {
    float acc = bgc[c];
    for (int k = 0; k < HD; k++) acc = fmaf(sh[k], Wgc[k * 4 + c], acc);
    out[g * 4 + c] = acc;
  }
}

extern "C" void kernel_launch(void* const* d_in, const int* in_sizes, int n_in,
                              void* d_out, int out_size, void* d_ws, size_t ws_size,
                              hipStream_t stream) {
  const float* node_feat = (const float*)d_in[0];
  const float* nodetype = (const float*)d_in[1];
  // d_in[2] edge_feat: dead branch, unused
  const float* W1 = (const float*)d_in[3];
  const float* b1 = (const float*)d_in[4];
  const float* g1 = (const float*)d_in[5];
  const float* be1 = (const float*)d_in[6];
  const float* W2 = (const float*)d_in[7];
  const float* b2 = (const float*)d_in[8];
  const float* g2 = (const float*)d_in[9];
  const float* be2 = (const float*)d_in[10];
  // 11 We, 12 b_e: dead
  const float* Wn1 = (const float*)d_in[13];
  const float* bn1 = (const float*)d_in[14];
  const float* Wn2 = (const float*)d_in[15];
  const float* bn2 = (const float*)d_in[16];
  const float* Wnc = (const float*)d_in[17];
  const float* bnc = (const float*)d_in[18];
  const float* Wg1 = (const float*)d_in[19];
  const float* bg1 = (const float*)d_in[20];
  const float* Wgc = (const float*)d_in[21];
  const float* bgc = (const float*)d_in[22];
  const int* src = (const int*)d_in[23];
  const int* dst = (const int*)d_in[24];
  const int* gid = (const int*)d_in[25];

  const int n = NN, e = NE;

  // ---- workspace carve (256B aligned) ----
  char* w = (char*)d_ws;
  auto alloc = [&](size_t bytes) -> void* {
    void* p = (void*)w;
    w += (bytes + 255) & ~(size_t)255;
    return p;
  };
  _Float16* T1 = (_Float16*)alloc((size_t)n * HD * 4);  // fp16 mm out; aliases deghist partials (dead before L1)
  float* AX = (float*)alloc((size_t)n * HD * 4);        // L1/L3/L4/L5 agg out (disjoint live ranges)
  float* A2 = (float*)alloc((size_t)n * HD * 4);        // L2 agg out; prologue aliases fill offsets
  int* hpart = (int*)T1;                                // 4*HNB*25000*4 B = 25.6 MB == sizeof(T1 region)
  int* offs = (int*)A2;                                 // 2*HNB*25000*4 B = 12.8 MB; dead before L2 agg
  int* csr_src = (int*)alloc((size_t)e * 4);
  int* row_ptr = (int*)alloc((size_t)(n + 1) * 4);
  int* incnt = (int*)alloc((size_t)n * 4);
  int* excl = (int*)alloc((size_t)n * 4);
  int* bsum = (int*)alloc(256 * 4);
  float* rs_out = (float*)alloc((size_t)n * 4);
  float* rs_in = (float*)alloc((size_t)n * 4);
  float* sums = (float*)alloc(256 * 4);
  float* bnp1 = (float*)alloc(256 * 4);
  float* bnp2 = (float*)alloc(256 * 4);
  unsigned short* Wp = (unsigned short*)alloc(5 * 32768 * 2);
  float* partial = (float*)alloc((size_t)64 * GK * HD * 4);

  const int NB = (n + 255) / 256;
  const int MMB = (n + 63) / 64;
  const int AGB = (n + 3) / 4;
  const int NOB = (n * 8 + 255) / 256;

  // ---- weight pack ----
  convw_kernel<<<5, 256, 0, stream>>>(W1, W2, Wn1, Wn2, Wg1, Wp);

  // ---- degrees + CSR build (fully atomic-free on global memory) ----
  deghist_kernel<<<HNB * 4, 256, 0, stream>>>(src, dst, hpart, e);
  degred_kernel<<<NB, 256, 0, stream>>>(hpart, incnt, rs_out, rs_in, n);
  scan1_kernel<<<NB, 256, 0, stream>>>(incnt, excl, bsum, n);
  scan2_kernel<<<1, 256, 0, stream>>>(bsum, NB);
  scan3_kernel<<<NB, 256, 0, stream>>>(excl, bsum, row_ptr, n, e);
  scanoffs_kernel<<<NB, 256, 0, stream>>>(hpart, row_ptr, offs, n);
  fill2_kernel<<<HNB * 2, 256, 0, stream>>>(src, dst, offs, csr_src, e);

  // ---- layer 1 ----
  mmfma_kernel<0><<<MMB, 256, 0, stream>>>(node_feat, nullptr, Wp + 0 * 32768, rs_out, nullptr, nullptr, T1, n);
  agg_kernel<<<AGB, 256, 0, stream>>>(T1, row_ptr, csr_src, rs_in, b1, AX, n, 0);
  hipMemsetAsync(sums, 0, 256 * 4, stream);
  stats_kernel<<<256, 256, 0, stream>>>(AX, n, sums);
  bnfin_kernel<<<1, 128, 0, stream>>>(sums, g1, be1, bnp1, (float)n);

  // ---- layer 2 (BN1+lrelu fused into mm read) ----
  mmfma_kernel<1><<<MMB, 256, 0, stream>>>(AX, bnp1, Wp + 1 * 32768, rs_out, nullptr, nullptr, T1, n);
  agg_kernel<<<AGB, 256, 0, stream>>>(T1, row_ptr, csr_src, rs_in, b2, A2, n, 0);
  hipMemsetAsync(sums, 0, 256 * 4, stream);
  stats_kernel<<<256, 256, 0, stream>>>(A2, n, sums);
  bnfin_kernel<<<1, 128, 0, stream>>>(sums, g2, be2, bnp2, (float)n);

  // ---- layer 3 (BN2 fused into mm read) ----
  mmfma_kernel<1><<<MMB, 256, 0, stream>>>(A2, bnp2, Wp + 2 * 32768, rs_out, nullptr, nullptr, T1, n);
  agg_kernel<<<AGB, 256, 0, stream>>>(T1, row_ptr, csr_src, rs_in, bn1, AX, n, 1);

  // ---- layer 4 ----
  mmfma_kernel<0><<<MMB, 256, 0, stream>>>(AX, nullptr, Wp + 3 * 32768, rs_out, nullptr, nullptr, T1, n);
  agg_kernel<<<AGB, 256, 0, stream>>>(T1, row_ptr, csr_src, rs_in, bn2, AX, n, 1);

  // ---- node_out ----
  nodeout_kernel<<<NOB, 256, 0, stream>>>(AX, Wnc, bnc, (float*)d_out, n);

  // ---- layer 5 (rank-1 fold; BN2 fused) ----
  mmfma_kernel<1><<<MMB, 256, 0, stream>>>(A2, bnp2, Wp + 4 * 32768, rs_out, nodetype, Wg1 + HD * HD, T1, n);
  agg_kernel<<<AGB, 256, 0, stream>>>(T1, row_ptr, csr_src, rs_in, bg1, AX, n, 1);

  // ---- graph mean (two-stage, no atomics) + graph_out ----
  gpart_kernel<<<64 * GK, 256, 0, stream>>>(AX, gid, partial, n);
  gfin_kernel<<<64, 128, 0, stream>>>(partial, gid, Wgc, bgc, (float*)d_out + (size_t)n * 8, n);
}